// Round 4
// baseline (140386.084 us; speedup 1.0000x reference)
//
#include <hip/hip_runtime.h>
#include <math.h>

#define BB 64
#define LL 256
#define EE 512
#define HH 1024
#define MM 2048
#define HSZ 64
#define RR 4
#define CIN 768
#define PO 1280
#define OO 1024
#define EPSF 1e-5f
#define NCHP 4          // chunks per batch row in mem phases
#define CSL 512         // slots per chunk
#define NBLK 256        // max grid

// ---- d_out layout (float offsets) ----
#define OUT_Y    0
#define OUT_MEM  (BB * LL * OO)
#define OUT_HT   (OUT_MEM + BB * MM * HSZ)
#define OUT_CT   (OUT_HT + BB * HH)

struct Params {
  const float *x_emb, *ln_in_g, *ln_in_b, *w_ih, *w_hh, *b_ih, *b_hh;
  const float *ln_c_g, *ln_c_b, *w_rk, *b_rk, *w_wk, *b_wk, *w_ws, *b_ws;
  const float *w_er, *b_er, *w_ad, *b_ad, *ln_rk_g, *ln_rk_b, *ln_wk_g, *ln_wk_b;
  const float *ln_m_g, *ln_m_b, *ln_o_g, *ln_o_b, *w_p, *b_p;
  float *y, *mem, *ht, *ct;
  float *h, *c, *hn, *ci, *rkn, *wkn, *ers, *ads, *wss, *wpart, *rmaxb, *rsumb, *rpvec, *orow, *s_w;
  unsigned *bar;
};

__device__ __forceinline__ float sigm(float x){ return 1.f/(1.f+expf(-x)); }

// device-scope grid barrier: sense-reversing, safe for any co-resident gridDim.x
__device__ __forceinline__ void gbar(unsigned* bar) {
  __syncthreads();
  if (threadIdx.x == 0) {
    __threadfence();   // release
    unsigned g = __hip_atomic_load(bar + 1, __ATOMIC_RELAXED, __HIP_MEMORY_SCOPE_AGENT);
    unsigned a = __hip_atomic_fetch_add(bar, 1u, __ATOMIC_ACQ_REL, __HIP_MEMORY_SCOPE_AGENT) + 1u;
    if (a == (unsigned)gridDim.x) {
      __hip_atomic_store(bar, 0u, __ATOMIC_RELAXED, __HIP_MEMORY_SCOPE_AGENT);
      __hip_atomic_fetch_add(bar + 1, 1u, __ATOMIC_RELEASE, __HIP_MEMORY_SCOPE_AGENT);
    } else {
      while (__hip_atomic_load(bar + 1, __ATOMIC_ACQUIRE, __HIP_MEMORY_SCOPE_AGENT) == g) {
        __builtin_amdgcn_s_sleep(8);
      }
    }
    __threadfence();   // acquire
  }
  __syncthreads();
}

__device__ __forceinline__ float bsum(float v, volatile float* red){
  __syncthreads();
  for (int o=32;o>0;o>>=1) v += __shfl_down(v,o,64);
  int w = threadIdx.x>>6;
  if ((threadIdx.x&63)==0) red[w]=v;
  __syncthreads();
  return red[0]+red[1]+red[2]+red[3];
}
__device__ __forceinline__ float bmax(float v, volatile float* red){
  __syncthreads();
  for (int o=32;o>0;o>>=1) v = fmaxf(v,__shfl_down(v,o,64));
  int w = threadIdx.x>>6;
  if ((threadIdx.x&63)==0) red[w]=v;
  __syncthreads();
  return fmaxf(fmaxf(red[0],red[1]),fmaxf(red[2],red[3]));
}

// LN stats + dot(LN(row), wk) for a 64-wide row held as 16 float4 in regs
__device__ __forceinline__ float row_score(const float4* v, const float* wk,
                                           const float* g, const float* bt){
  float sum=0.f;
  #pragma unroll
  for (int i=0;i<16;++i) sum += v[i].x+v[i].y+v[i].z+v[i].w;
  float mu = sum*(1.f/64.f);
  float ssq=0.f;
  #pragma unroll
  for (int i=0;i<16;++i){ float dx=v[i].x-mu,dy=v[i].y-mu,dz=v[i].z-mu,dw=v[i].w-mu;
                          ssq+=dx*dx+dy*dy+dz*dz+dw*dw; }
  float rstd = rsqrtf(ssq*(1.f/64.f)+EPSF);
  float sc=0.f;
  #pragma unroll
  for (int i=0;i<16;++i){ int h=i*4;
    sc += ((v[i].x-mu)*rstd*g[h  ]+bt[h  ])*wk[h  ];
    sc += ((v[i].y-mu)*rstd*g[h+1]+bt[h+1])*wk[h+1];
    sc += ((v[i].z-mu)*rstd*g[h+2]+bt[h+2])*wk[h+2];
    sc += ((v[i].w-mu)*rstd*g[h+3]+bt[h+3])*wk[h+3];
  }
  return sc;
}

__device__ void logits_tile(const Params& p, int w, int tid, int tprev, float* sA){
  int cgl = w & 15, bg = w >> 4;
  int tb = tid >> 4, cq = tid & 15;
  int b0 = bg*16, col0 = cgl*64;
  float (*A)[68]  = (float(*)[68])sA;
  float (*Wt)[68] = (float(*)[68])(sA+1088);
  float acc0=0,acc1=0,acc2=0,acc3=0;
  int c0 = cq*4;
  for (int k0=0;k0<PO;k0+=64){
    __syncthreads();
    { int ar=tid>>4, ac=(tid&15)<<2;
      float4 a4 = *(const float4*)&p.orow[(b0+ar)*PO + k0 + ac];
      *(float4*)&A[ar][ac]=a4; }
    for (int i=0;i<4;++i){
      int idx=i*256+tid; int cc=idx>>4; int kq=(idx&15)<<2;
      float4 w4 = *(const float4*)&p.w_p[(size_t)(col0+cc)*PO + k0 + kq];
      Wt[kq+0][cc]=w4.x; Wt[kq+1][cc]=w4.y; Wt[kq+2][cc]=w4.z; Wt[kq+3][cc]=w4.w;
    }
    __syncthreads();
    #pragma unroll
    for (int kk=0;kk<16;++kk){
      float4 a4 = *(const float4*)&A[tb][kk*4];
      float4 wv;
      wv=*(const float4*)&Wt[kk*4+0][c0]; acc0+=a4.x*wv.x; acc1+=a4.x*wv.y; acc2+=a4.x*wv.z; acc3+=a4.x*wv.w;
      wv=*(const float4*)&Wt[kk*4+1][c0]; acc0+=a4.y*wv.x; acc1+=a4.y*wv.y; acc2+=a4.y*wv.z; acc3+=a4.y*wv.w;
      wv=*(const float4*)&Wt[kk*4+2][c0]; acc0+=a4.z*wv.x; acc1+=a4.z*wv.y; acc2+=a4.z*wv.z; acc3+=a4.z*wv.w;
      wv=*(const float4*)&Wt[kk*4+3][c0]; acc0+=a4.w*wv.x; acc1+=a4.w*wv.y; acc2+=a4.w*wv.z; acc3+=a4.w*wv.w;
    }
  }
  int col = col0 + c0;
  float4 o;
  o.x=acc0+p.b_p[col]; o.y=acc1+p.b_p[col+1]; o.z=acc2+p.b_p[col+2]; o.w=acc3+p.b_p[col+3];
  *(float4*)&p.y[(size_t)((b0+tb)*LL + tprev)*OO + col] = o;
}

__global__ __launch_bounds__(256, 1) void dnc_all(Params p) {
  __shared__ __align__(16) float sA[6528];
  __shared__ __align__(16) float scr[4*CSL];
  __shared__ __align__(16) float sbuf[64*66];
  __shared__ float sred[8];
  const int blk = blockIdx.x, tid = threadIdx.x;
  const int NB = gridDim.x;
  const int gsz = NB * 256;

  // ---------------- P0: init ----------------
  {
    float4 z4 = make_float4(0.f,0.f,0.f,0.f);
    float4* m4 = (float4*)p.mem;
    int gidx = blk*256 + tid;
    for (int i = gidx; i < (BB*MM*HSZ)/4; i += gsz) m4[i] = z4;
    for (int i = gidx; i < (BB*HH)/4; i += gsz) { ((float4*)p.h)[i] = z4; ((float4*)p.c)[i] = z4; }
    for (int b = blk; b < BB; b += NB) {
      __syncthreads();
      for (int i = tid; i < CIN; i += 256)
        sA[i] = (i < EE) ? p.x_emb[(size_t)(b*LL)*EE + i] : 0.f;
      __syncthreads();
      float s = 0.f;
      for (int i = tid; i < CIN; i += 256) s += sA[i];
      float mu = bsum(s, sred) * (1.f/CIN);
      float ss = 0.f;
      for (int i = tid; i < CIN; i += 256) { float d = sA[i]-mu; ss += d*d; }
      float rstd = rsqrtf(bsum(ss, sred)*(1.f/CIN) + EPSF);
      for (int i = tid; i < CIN; i += 256)
        p.ci[b*CIN+i] = (sA[i]-mu)*rstd*p.ln_in_g[i] + p.ln_in_b[i];
    }
  }
  gbar(p.bar);

  for (int t = 0; t < LL; ++t) {
    const float* hprev = p.h + (t & 1) * (BB*HH);
    float* hnew = p.h + ((t+1) & 1) * (BB*HH);

    // ---------------- P1: gates GEMM + LSTM (256 tiles) ----------------
    for (int w = blk; w < 256; w += NB) {
      int cgp = w & 63, bg = w >> 6;
      int tb = tid >> 4, cq = tid & 15;
      int b0 = bg*16, j0 = cgp*16;
      float (*A)[68]  = (float(*)[68])sA;
      float (*Wt)[68] = (float(*)[68])(sA + 1088);
      float (*Gv)[68] = (float(*)[68])(sA + 5440);
      float acc0=0,acc1=0,acc2=0,acc3=0;
      int c0 = cq*4;
      for (int ph = 0; ph < 2; ++ph) {
        const float* Asrc = ph ? hprev : p.ci;
        const float* Wsrc = ph ? p.w_hh : p.w_ih;
        int K = ph ? HH : CIN;
        for (int k0 = 0; k0 < K; k0 += 64) {
          __syncthreads();
          { int ar = tid>>4, ac = (tid&15)<<2;
            float4 a4 = *(const float4*)&Asrc[(b0+ar)*K + k0 + ac];
            *(float4*)&A[ar][ac] = a4; }
          for (int i=0;i<4;++i){
            int idx2 = i*256+tid;
            int cc = idx2>>4, kq = (idx2&15)<<2;
            int gate = cc>>4, jl = cc&15;
            float4 w4 = *(const float4*)&Wsrc[(size_t)(gate*HH + j0 + jl)*K + k0 + kq];
            Wt[kq+0][cc]=w4.x; Wt[kq+1][cc]=w4.y; Wt[kq+2][cc]=w4.z; Wt[kq+3][cc]=w4.w;
          }
          __syncthreads();
          #pragma unroll
          for (int kk=0;kk<16;++kk){
            float4 a4 = *(const float4*)&A[tb][kk*4];
            float4 wv;
            wv=*(const float4*)&Wt[kk*4+0][c0]; acc0+=a4.x*wv.x; acc1+=a4.x*wv.y; acc2+=a4.x*wv.z; acc3+=a4.x*wv.w;
            wv=*(const float4*)&Wt[kk*4+1][c0]; acc0+=a4.y*wv.x; acc1+=a4.y*wv.y; acc2+=a4.y*wv.z; acc3+=a4.y*wv.w;
            wv=*(const float4*)&Wt[kk*4+2][c0]; acc0+=a4.z*wv.x; acc1+=a4.z*wv.y; acc2+=a4.z*wv.z; acc3+=a4.z*wv.w;
            wv=*(const float4*)&Wt[kk*4+3][c0]; acc0+=a4.w*wv.x; acc1+=a4.w*wv.y; acc2+=a4.w*wv.z; acc3+=a4.w*wv.w;
          }
        }
      }
      { int gate = c0>>4; int r = gate*HH + j0 + (c0&15);
        acc0 += p.b_ih[r]+p.b_hh[r];     acc1 += p.b_ih[r+1]+p.b_hh[r+1];
        acc2 += p.b_ih[r+2]+p.b_hh[r+2]; acc3 += p.b_ih[r+3]+p.b_hh[r+3]; }
      Gv[tb][c0]=acc0; Gv[tb][c0+1]=acc1; Gv[tb][c0+2]=acc2; Gv[tb][c0+3]=acc3;
      __syncthreads();
      { int jl = cq;
        float gi=Gv[tb][jl], gf=Gv[tb][16+jl], gg=Gv[tb][32+jl], go=Gv[tb][48+jl];
        int idx3 = (b0+tb)*HH + j0 + jl;
        float cold = p.c[idx3];
        float cn = sigm(gf)*cold + sigm(gi)*tanhf(gg);
        p.c[idx3] = cn;
        hnew[idx3] = sigm(go)*tanhf(cn);
      }
      __syncthreads();
    }
    gbar(p.bar);

    // ---------------- P2: hn LN + heads (256 tiles) + logits(t-1) (64 tiles) ----------------
    for (int w = blk; w < 256; w += NB) {
      int b = w >> 2, q = w & 3;
      float* hrow = sA;          // 1024
      float* raw  = sA + 1024;   // up to 129
      __syncthreads();
      ((float4*)hrow)[tid] = ((const float4*)&hnew[b*HH])[tid];
      __syncthreads();
      float s=0.f; for (int i=tid;i<HH;i+=256) s += hrow[i];
      float mu = bsum(s,sred)*(1.f/HH);
      float ss=0.f; for (int i=tid;i<HH;i+=256){ float d=hrow[i]-mu; ss+=d*d; }
      float rstd = rsqrtf(bsum(ss,sred)*(1.f/HH)+EPSF);
      for (int i=tid;i<HH;i+=256){
        float v=(hrow[i]-mu)*rstd*p.ln_c_g[i]+p.ln_c_b[i];
        hrow[i]=v;
        if (q==0) p.hn[b*HH+i]=v;
      }
      __syncthreads();
      int base = (q==0)?0 : (q==1)?128 : (q==2)?256 : 385;
      int cnt  = (q==2)?129 : (q==3)?64 : 128;
      if (tid < cnt) {
        int gr = base + tid;
        const float* wrow; float bias;
        if (gr < 256)      { wrow = p.w_rk + (size_t)gr*HH;        bias = p.b_rk[gr]; }
        else if (gr < 320) { wrow = p.w_wk + (size_t)(gr-256)*HH;  bias = p.b_wk[gr-256]; }
        else if (gr == 320){ wrow = p.w_ws;                        bias = p.b_ws[0]; }
        else if (gr < 385) { wrow = p.w_er + (size_t)(gr-321)*HH;  bias = p.b_er[gr-321]; }
        else               { wrow = p.w_ad + (size_t)(gr-385)*HH;  bias = p.b_ad[gr-385]; }
        float acc = bias;
        #pragma unroll 8
        for (int k=0;k<HH;k+=4){
          float4 w4 = *(const float4*)&wrow[k];
          acc += w4.x*hrow[k]+w4.y*hrow[k+1]+w4.z*hrow[k+2]+w4.w*hrow[k+3];
        }
        raw[tid] = acc;
      }
      __syncthreads();
      if (q < 2) {
        if (tid < 128) {
          int g2 = tid>>6, l = tid&63;
          int head = q*2 + g2;
          float v = raw[g2*64 + l];
          float sv=v; for(int o=32;o>0;o>>=1) sv += __shfl_xor(sv,o,64);
          float m2 = sv*(1.f/64.f);
          float d = v-m2; float sq=d*d;
          for(int o=32;o>0;o>>=1) sq += __shfl_xor(sq,o,64);
          float rs = rsqrtf(sq*(1.f/64.f)+EPSF);
          p.rkn[(b*RR+head)*HSZ + l] = d*rs*p.ln_rk_g[l] + p.ln_rk_b[l];
        }
      } else if (q == 2) {
        if (tid < 64) {
          float v = raw[tid];
          float sv=v; for(int o=32;o>0;o>>=1) sv += __shfl_xor(sv,o,64);
          float m2 = sv*(1.f/64.f);
          float d=v-m2; float sq=d*d;
          for(int o=32;o>0;o>>=1) sq += __shfl_xor(sq,o,64);
          float rs = rsqrtf(sq*(1.f/64.f)+EPSF);
          p.wkn[b*HSZ+tid] = d*rs*p.ln_wk_g[tid] + p.ln_wk_b[tid];
          p.ers[b*HSZ+tid] = sigm(raw[65+tid]);
          if (tid==0) p.wss[b] = sigm(raw[64]);
        }
      } else {
        if (tid < 64) p.ads[b*HSZ+tid] = tanhf(raw[tid]);
      }
      __syncthreads();
    }
    if (t > 0) {
      for (int w = blk; w < 64; w += NB) logits_tile(p, w, tid, t-1, sA);
    }
    gbar(p.bar);

    // ---------------- P3: write scores (256 tiles) ----------------
    for (int w = blk; w < 256; w += NB) {
      int bP = w >> 2, chP = w & 3;
      __syncthreads();
      if (tid < 64) { sA[tid]=p.wkn[bP*HSZ+tid]; sA[64+tid]=p.ln_m_g[tid]; sA[128+tid]=p.ln_m_b[tid]; }
      __syncthreads();
      int s0 = chP*CSL + tid*2;
      const float* row0 = p.mem + (size_t)(bP*MM + s0)*HSZ;
      float4 rr[32];
      #pragma unroll
      for (int j=0;j<16;++j) rr[j]    = ((const float4*)row0)[j];
      #pragma unroll
      for (int j=0;j<16;++j) rr[16+j] = ((const float4*)(row0+HSZ))[j];
      float wsc0 = row_score(rr,    sA, sA+64, sA+128);
      float wsc1 = row_score(rr+16, sA, sA+64, sA+128);
      p.s_w[bP*MM + s0]     = wsc0;
      p.s_w[bP*MM + s0 + 1] = wsc1;
      float mx = bmax(fmaxf(wsc0,wsc1), sred);
      float se = bsum(expf(wsc0-mx)+expf(wsc1-mx), sred);
      if (tid==0){ p.wpart[(bP*NCHP+chP)*2]=mx; p.wpart[(bP*NCHP+chP)*2+1]=se; }
    }
    gbar(p.bar);

    // ---------------- P4: mem update + read scores + weighted partials (256 tiles) ----------------
    for (int w = blk; w < 256; w += NB) {
      int bP = w >> 2, chP = w & 3;
      __syncthreads();
      if (tid < 64) { sA[tid]=p.ers[bP*HSZ+tid]; sA[64+tid]=p.ads[bP*HSZ+tid];
                      sA[128+tid]=p.ln_m_g[tid]; sA[192+tid]=p.ln_m_b[tid]; }
      sA[256+tid] = p.rkn[bP*RR*HSZ + tid];
      __syncthreads();
      float gmx = -3.4e38f, gsum = 0.f;
      #pragma unroll
      for (int cc2=0;cc2<NCHP;++cc2) gmx = fmaxf(gmx, p.wpart[(bP*NCHP+cc2)*2]);
      #pragma unroll
      for (int cc2=0;cc2<NCHP;++cc2)
        gsum += p.wpart[(bP*NCHP+cc2)*2+1]*expf(p.wpart[(bP*NCHP+cc2)*2]-gmx);
      float wstr = p.wss[bP];
      int s0 = chP*CSL + tid*2;
      float* row0 = p.mem + (size_t)(bP*MM+s0)*HSZ;
      float4 rr[32];
      #pragma unroll
      for (int j=0;j<16;++j) rr[j]    = ((const float4*)row0)[j];
      #pragma unroll
      for (int j=0;j<16;++j) rr[16+j] = ((const float4*)(row0+HSZ))[j];
      float wsc0 = p.s_w[bP*MM + s0], wsc1 = p.s_w[bP*MM + s0 + 1];
      float rsc[4][2];
      #pragma unroll
      for (int r=0;r<2;++r){
        float ww = expf(((r==0)?wsc0:wsc1)-gmx)/gsum*wstr;
        float4* v = rr + r*16;
        #pragma unroll
        for (int i=0;i<16;++i){ int h=i*4;
          v[i].x = v[i].x*(1.f-ww*sA[h  ]) + ww*sA[64+h  ];
          v[i].y = v[i].y*(1.f-ww*sA[h+1]) + ww*sA[64+h+1];
          v[i].z = v[i].z*(1.f-ww*sA[h+2]) + ww*sA[64+h+2];
          v[i].w = v[i].w*(1.f-ww*sA[h+3]) + ww*sA[64+h+3];
        }
        float* dst = row0 + r*HSZ;
        #pragma unroll
        for (int i=0;i<16;++i) ((float4*)dst)[i] = v[i];
        float sum=0.f;
        #pragma unroll
        for (int i=0;i<16;++i) sum += v[i].x+v[i].y+v[i].z+v[i].w;
        float muv = sum*(1.f/64.f);
        float ssq=0.f;
        #pragma unroll
        for (int i=0;i<16;++i){ float dx=v[i].x-muv,dy=v[i].y-muv,dz=v[i].z-muv,dw=v[i].w-muv;
                                ssq+=dx*dx+dy*dy+dz*dz+dw*dw; }
        float rstd=rsqrtf(ssq*(1.f/64.f)+EPSF);
        float t0=0,t1=0,t2=0,t3=0;
        #pragma unroll
        for (int i=0;i<16;++i){ int h=i*4;
          float n0=(v[i].x-muv)*rstd*sA[128+h  ]+sA[192+h  ];
          float n1=(v[i].y-muv)*rstd*sA[128+h+1]+sA[192+h+1];
          float n2=(v[i].z-muv)*rstd*sA[128+h+2]+sA[192+h+2];
          float n3=(v[i].w-muv)*rstd*sA[128+h+3]+sA[192+h+3];
          t0 += n0*sA[256+h]+n1*sA[256+h+1]+n2*sA[256+h+2]+n3*sA[256+h+3];
          t1 += n0*sA[320+h]+n1*sA[320+h+1]+n2*sA[320+h+2]+n3*sA[320+h+3];
          t2 += n0*sA[384+h]+n1*sA[384+h+1]+n2*sA[384+h+2]+n3*sA[384+h+3];
          t3 += n0*sA[448+h]+n1*sA[448+h+1]+n2*sA[448+h+2]+n3*sA[448+h+3];
        }
        rsc[0][r]=t0; rsc[1][r]=t1; rsc[2][r]=t2; rsc[3][r]=t3;
      }
      float mxn[4], sen[4];
      #pragma unroll
      for (int n=0;n<4;++n){
        mxn[n] = bmax(fmaxf(rsc[n][0],rsc[n][1]), sred);
        sen[n] = bsum(expf(rsc[n][0]-mxn[n])+expf(rsc[n][1]-mxn[n]), sred);
      }
      if (tid==0){
        #pragma unroll
        for (int n=0;n<4;++n){
          p.rmaxb[(bP*RR+n)*NCHP+chP]=mxn[n];
          p.rsumb[(bP*RR+n)*NCHP+chP]=sen[n];
        }
      }
      int ls = tid*2;
      #pragma unroll
      for (int n=0;n<4;++n){
        scr[n*CSL+ls]  =expf(rsc[n][0]-mxn[n]);
        scr[n*CSL+ls+1]=expf(rsc[n][1]-mxn[n]);
      }
      __syncthreads();
      int mi = tid>>6, hs = tid&63;
      float a0=0,a1=0,a2=0,a3=0;
      for (int c8=0;c8<8;++c8){
        if ((tid>>5)==c8){
          int lr = (tid&31)*2;
          float* d0 = sbuf + lr*66;
          float* d1 = sbuf + (lr+1)*66;
          #pragma unroll
          for (int i=0;i<16;++i){
            ((float2*)d0)[i*2]   = make_float2(rr[i].x,    rr[i].y);
            ((float2*)d0)[i*2+1] = make_float2(rr[i].z,    rr[i].w);
            ((float2*)d1)[i*2]   = make_float2(rr[16+i].x, rr[16+i].y);
            ((float2*)d1)[i*2+1] = make_float2(rr[16+i].z, rr[16+i].w);
          }
        }
        __syncthreads();
        #pragma unroll
        for (int k=0;k<16;++k){
          int slc = mi + k*4;
          int sl  = c8*64 + slc;
          float v = sbuf[slc*66 + hs];
          a0 += scr[sl]*v; a1 += scr[CSL+sl]*v; a2 += scr[2*CSL+sl]*v; a3 += scr[3*CSL+sl]*v;
        }
        __syncthreads();
      }
      sbuf[(mi*4+0)*66+hs]=a0; sbuf[(mi*4+1)*66+hs]=a1;
      sbuf[(mi*4+2)*66+hs]=a2; sbuf[(mi*4+3)*66+hs]=a3;
      __syncthreads();
      { int n = tid>>6, h2 = tid&63;
        float v = sbuf[(0*4+n)*66+h2]+sbuf[(1*4+n)*66+h2]+sbuf[(2*4+n)*66+h2]+sbuf[(3*4+n)*66+h2];
        p.rpvec[((bP*RR+n)*NCHP+chP)*HSZ + h2] = v;
      }
      __syncthreads();
    }
    gbar(p.bar);

    // ---------------- P5: rv reduce + orow LN + ci(t+1) (64 tiles) ----------------
    for (int b = blk; b < BB; b += NB) {
      int n = tid>>6, h2 = tid&63;
      __syncthreads();
      float gmx = -3.4e38f;
      #pragma unroll
      for (int cc2=0;cc2<NCHP;++cc2) gmx = fmaxf(gmx, p.rmaxb[(b*RR+n)*NCHP+cc2]);
      float den=0.f, num=0.f;
      #pragma unroll
      for (int cc2=0;cc2<NCHP;++cc2){
        float e = expf(p.rmaxb[(b*RR+n)*NCHP+cc2]-gmx);
        den += p.rsumb[(b*RR+n)*NCHP+cc2]*e;
        num += p.rpvec[((b*RR+n)*NCHP+cc2)*HSZ+h2]*e;
      }
      float rvv = num/den;
      float* row = sA;          // 1280
      float* cirow = sA+1280;   // 768
      row[HH+tid] = rvv;
      for (int i=tid;i<HH;i+=256) row[i] = p.hn[b*HH+i];
      __syncthreads();
      float s=0.f; for (int i=tid;i<PO;i+=256) s+=row[i];
      float mu = bsum(s,sred)*(1.f/PO);
      float ss=0.f; for (int i=tid;i<PO;i+=256){float d=row[i]-mu; ss+=d*d;}
      float rstd = rsqrtf(bsum(ss,sred)*(1.f/PO)+EPSF);
      for (int i=tid;i<PO;i+=256)
        p.orow[b*PO+i] = (row[i]-mu)*rstd*p.ln_o_g[i]+p.ln_o_b[i];
      if (t+1 < LL) {
        for (int i=tid;i<CIN;i+=256)
          cirow[i] = (i<EE)? p.x_emb[(size_t)(b*LL+t+1)*EE+i] : row[HH+(i-EE)];
        __syncthreads();
        float s2=0.f; for (int i=tid;i<CIN;i+=256) s2+=cirow[i];
        float mu2 = bsum(s2,sred)*(1.f/CIN);
        float ss2=0.f; for (int i=tid;i<CIN;i+=256){float d=cirow[i]-mu2; ss2+=d*d;}
        float rstd2 = rsqrtf(bsum(ss2,sred)*(1.f/CIN)+EPSF);
        for (int i=tid;i<CIN;i+=256)
          p.ci[b*CIN+i] = (cirow[i]-mu2)*rstd2*p.ln_in_g[i]+p.ln_in_b[i];
      }
      __syncthreads();
    }
    gbar(p.bar);
  }

  // ---------------- final: logits(255) + ht/ct ----------------
  for (int w = blk; w < 64; w += NB) logits_tile(p, w, tid, LL-1, sA);
  {
    int gidx = blk*256 + tid;
    for (int i = gidx; i < (BB*HH)/4; i += gsz) {
      ((float4*)p.ht)[i] = ((const float4*)p.h)[i];
      ((float4*)p.ct)[i] = ((const float4*)p.c)[i];
    }
  }
}

extern "C" void kernel_launch(void* const* d_in, const int* in_sizes, int n_in,
                              void* d_out, int out_size, void* d_ws, size_t ws_size,
                              hipStream_t stream) {
  Params prm;
  prm.x_emb  = (const float*)d_in[0];
  prm.ln_in_g= (const float*)d_in[1];
  prm.ln_in_b= (const float*)d_in[2];
  prm.w_ih   = (const float*)d_in[3];
  prm.w_hh   = (const float*)d_in[4];
  prm.b_ih   = (const float*)d_in[5];
  prm.b_hh   = (const float*)d_in[6];
  prm.ln_c_g = (const float*)d_in[7];
  prm.ln_c_b = (const float*)d_in[8];
  prm.w_rk   = (const float*)d_in[9];
  prm.b_rk   = (const float*)d_in[10];
  prm.w_wk   = (const float*)d_in[11];
  prm.b_wk   = (const float*)d_in[12];
  prm.w_ws   = (const float*)d_in[13];
  prm.b_ws   = (const float*)d_in[14];
  prm.w_er   = (const float*)d_in[15];
  prm.b_er   = (const float*)d_in[16];
  prm.w_ad   = (const float*)d_in[17];
  prm.b_ad   = (const float*)d_in[18];
  prm.ln_rk_g= (const float*)d_in[19];
  prm.ln_rk_b= (const float*)d_in[20];
  prm.ln_wk_g= (const float*)d_in[21];
  prm.ln_wk_b= (const float*)d_in[22];
  prm.ln_m_g = (const float*)d_in[23];
  prm.ln_m_b = (const float*)d_in[24];
  prm.ln_o_g = (const float*)d_in[25];
  prm.ln_o_b = (const float*)d_in[26];
  prm.w_p    = (const float*)d_in[27];
  prm.b_p    = (const float*)d_in[28];

  float* out = (float*)d_out;
  prm.y   = out + OUT_Y;
  prm.mem = out + OUT_MEM;
  prm.ht  = out + OUT_HT;
  prm.ct  = out + OUT_CT;

  // barrier state in first 256 bytes of d_ws; re-zeroed every call (capture-legal)
  prm.bar = (unsigned*)d_ws;
  hipMemsetAsync(d_ws, 0, 256, stream);

  float* ws = (float*)((char*)d_ws + 256);
  size_t o = 0;
  prm.h     = ws + o; o += 2*BB*HH;
  prm.c     = ws + o; o += BB*HH;
  prm.hn    = ws + o; o += BB*HH;
  prm.ci    = ws + o; o += BB*CIN;
  prm.rkn   = ws + o; o += BB*RR*HSZ;
  prm.wkn   = ws + o; o += BB*HSZ;
  prm.ers   = ws + o; o += BB*HSZ;
  prm.ads   = ws + o; o += BB*HSZ;
  prm.wss   = ws + o; o += BB;
  prm.wpart = ws + o; o += BB*NCHP*2;
  prm.rmaxb = ws + o; o += BB*RR*NCHP;
  prm.rsumb = ws + o; o += BB*RR*NCHP;
  prm.rpvec = ws + o; o += BB*RR*NCHP*HSZ;
  prm.orow  = ws + o; o += BB*PO;
  prm.s_w   = ws + o; o += BB*MM;

  // size grid to guaranteed-co-resident block count (robust to partitioned devices)
  int dev = 0;
  hipGetDevice(&dev);
  int ncu = 0;
  hipDeviceGetAttribute(&ncu, hipDeviceAttributeMultiprocessorCount, dev);
  if (ncu <= 0) ncu = 64;
  int nb = ncu < NBLK ? ncu : NBLK;
  int nbp = 1;
  while (nbp * 2 <= nb) nbp *= 2;   // largest power of two <= nb (clean tile division)

  dnc_all<<<dim3(nbp), dim3(256), 0, stream>>>(prm);
}

// Round 5
// 81627.789 us; speedup vs baseline: 1.7198x; 1.7198x over previous
//
#include <hip/hip_runtime.h>
#include <math.h>

#define BB 64
#define LL 256
#define EE 512
#define HH 1024
#define MM 2048
#define HSZ 64
#define RR 4
#define CIN 768
#define PO 1280
#define OO 1024
#define EPSF 1e-5f
#define NBLK 256

// ---- d_out layout (float offsets) ----
#define OUT_Y    0
#define OUT_MEM  (BB * LL * OO)
#define OUT_HT   (OUT_MEM + BB * MM * HSZ)
#define OUT_CT   (OUT_HT + BB * HH)

struct Params {
  const float *x_emb, *ln_in_g, *ln_in_b, *w_ih, *w_hh, *b_ih, *b_hh;
  const float *ln_c_g, *ln_c_b, *w_rk, *b_rk, *w_wk, *b_wk, *w_ws, *b_ws;
  const float *w_er, *b_er, *w_ad, *b_ad, *ln_rk_g, *ln_rk_b, *ln_wk_g, *ln_wk_b;
  const float *ln_m_g, *ln_m_b, *ln_o_g, *ln_o_b, *w_p, *b_p;
  float *y, *mem, *ht, *ct;
  float *h, *c, *hn, *ci, *rkn, *wkn, *ers, *ads, *wss, *orow;
  unsigned *bar;
};

__device__ __forceinline__ float sigm(float x){ return 1.f/(1.f+expf(-x)); }

// Monotone count-up grid barrier. Poll with RELAXED loads (no cache maintenance);
// exactly one threadfence pair (wbl2 / inv) per block per barrier.
// Safe iff all gridDim.x blocks co-resident (grid sized to CU count).
__device__ __forceinline__ void gbar(unsigned* bar, unsigned target) {
  __syncthreads();
  if (threadIdx.x == 0) {
    __threadfence();   // release: write back this block's dirty lines
    __hip_atomic_fetch_add(bar, 1u, __ATOMIC_RELAXED, __HIP_MEMORY_SCOPE_AGENT);
    while (__hip_atomic_load(bar, __ATOMIC_RELAXED, __HIP_MEMORY_SCOPE_AGENT) < target) {
      __builtin_amdgcn_s_sleep(8);
    }
    __threadfence();   // acquire: invalidate so fresh data is fetched
  }
  __syncthreads();
}

__device__ __forceinline__ float bsum(float v, volatile float* red){
  __syncthreads();
  for (int o=32;o>0;o>>=1) v += __shfl_down(v,o,64);
  int w = threadIdx.x>>6;
  if ((threadIdx.x&63)==0) red[w]=v;
  __syncthreads();
  return red[0]+red[1]+red[2]+red[3];
}
__device__ __forceinline__ float bmax(float v, volatile float* red){
  __syncthreads();
  for (int o=32;o>0;o>>=1) v = fmaxf(v,__shfl_down(v,o,64));
  int w = threadIdx.x>>6;
  if ((threadIdx.x&63)==0) red[w]=v;
  __syncthreads();
  return fmaxf(fmaxf(red[0],red[1]),fmaxf(red[2],red[3]));
}

// LN stats + dot(LN(row), wk) for a 64-wide row held as 16 float4 in regs
__device__ __forceinline__ float row_score(const float4* v, const float* wk,
                                           const float* g, const float* bt){
  float sum=0.f;
  #pragma unroll
  for (int i=0;i<16;++i) sum += v[i].x+v[i].y+v[i].z+v[i].w;
  float mu = sum*(1.f/64.f);
  float ssq=0.f;
  #pragma unroll
  for (int i=0;i<16;++i){ float dx=v[i].x-mu,dy=v[i].y-mu,dz=v[i].z-mu,dw=v[i].w-mu;
                          ssq+=dx*dx+dy*dy+dz*dz+dw*dw; }
  float rstd = rsqrtf(ssq*(1.f/64.f)+EPSF);
  float sc=0.f;
  #pragma unroll
  for (int i=0;i<16;++i){ int h=i*4;
    sc += ((v[i].x-mu)*rstd*g[h  ]+bt[h  ])*wk[h  ];
    sc += ((v[i].y-mu)*rstd*g[h+1]+bt[h+1])*wk[h+1];
    sc += ((v[i].z-mu)*rstd*g[h+2]+bt[h+2])*wk[h+2];
    sc += ((v[i].w-mu)*rstd*g[h+3]+bt[h+3])*wk[h+3];
  }
  return sc;
}

__device__ void logits_tile(const Params& p, int w, int tid, int tprev, float* smem){
  int cgl = w & 15, bg = w >> 4;
  int tb = tid >> 4, cq = tid & 15;
  int b0 = bg*16, col0 = cgl*64;
  float (*A)[68]  = (float(*)[68])smem;
  float (*Wt)[68] = (float(*)[68])(smem+1088);
  float acc0=0,acc1=0,acc2=0,acc3=0;
  int c0 = cq*4;
  for (int k0=0;k0<PO;k0+=64){
    __syncthreads();
    { int ar=tid>>4, ac=(tid&15)<<2;
      float4 a4 = *(const float4*)&p.orow[(b0+ar)*PO + k0 + ac];
      *(float4*)&A[ar][ac]=a4; }
    for (int i=0;i<4;++i){
      int idx=i*256+tid; int cc=idx>>4; int kq=(idx&15)<<2;
      float4 w4 = *(const float4*)&p.w_p[(size_t)(col0+cc)*PO + k0 + kq];
      Wt[kq+0][cc]=w4.x; Wt[kq+1][cc]=w4.y; Wt[kq+2][cc]=w4.z; Wt[kq+3][cc]=w4.w;
    }
    __syncthreads();
    #pragma unroll
    for (int kk=0;kk<16;++kk){
      float4 a4 = *(const float4*)&A[tb][kk*4];
      float4 wv;
      wv=*(const float4*)&Wt[kk*4+0][c0]; acc0+=a4.x*wv.x; acc1+=a4.x*wv.y; acc2+=a4.x*wv.z; acc3+=a4.x*wv.w;
      wv=*(const float4*)&Wt[kk*4+1][c0]; acc0+=a4.y*wv.x; acc1+=a4.y*wv.y; acc2+=a4.y*wv.z; acc3+=a4.y*wv.w;
      wv=*(const float4*)&Wt[kk*4+2][c0]; acc0+=a4.z*wv.x; acc1+=a4.z*wv.y; acc2+=a4.z*wv.z; acc3+=a4.z*wv.w;
      wv=*(const float4*)&Wt[kk*4+3][c0]; acc0+=a4.w*wv.x; acc1+=a4.w*wv.y; acc2+=a4.w*wv.z; acc3+=a4.w*wv.w;
    }
  }
  int col = col0 + c0;
  float4 o;
  o.x=acc0+p.b_p[col]; o.y=acc1+p.b_p[col+1]; o.z=acc2+p.b_p[col+2]; o.w=acc3+p.b_p[col+3];
  *(float4*)&p.y[(size_t)((b0+tb)*LL + tprev)*OO + col] = o;
}

// full per-b memory pipeline: write scores -> exact softmax -> update -> read scores
// -> exact softmaxes -> rv gather -> orow LN -> ci(t+1) LN.  All block-local.
__device__ void mem_phase(const Params& p, int b, int tid, int t, float* smem, float* sred){
  float* bc  = smem;          // [576] broadcasts
  float* sw  = smem + 576;    // [2048] write scores -> write weights -> rv partials
  float* srd = smem + 2624;   // [4*2048] read scores -> read weights; then row/cirow
  if (tid < 64) {
    bc[tid]     = p.wkn[b*HSZ+tid];
    bc[64+tid]  = p.ln_m_g[tid];
    bc[128+tid] = p.ln_m_b[tid];
    bc[192+tid] = p.ers[b*HSZ+tid];
    bc[256+tid] = p.ads[b*HSZ+tid];
  }
  bc[320+tid] = p.rkn[b*RR*HSZ + tid];
  __syncthreads();
  float wstr = p.wss[b];
  float* mb = p.mem + (size_t)b*MM*HSZ;

  // pass A: write scores
  for (int k=0;k<8;++k){
    int m = k*256 + tid;
    const float4* row = (const float4*)(mb + (size_t)m*HSZ);
    float4 rr[16];
    #pragma unroll
    for (int j=0;j<16;++j) rr[j] = row[j];
    sw[m] = row_score(rr, bc, bc+64, bc+128);
  }
  __syncthreads();
  // exact block softmax over 2048
  float mx = -3.4e38f;
  for (int k=0;k<8;++k) mx = fmaxf(mx, sw[k*256+tid]);
  mx = bmax(mx, sred);
  float se = 0.f;
  for (int k=0;k<8;++k) se += expf(sw[k*256+tid]-mx);
  se = bsum(se, sred);
  float winv = wstr / se;
  for (int k=0;k<8;++k){ int m=k*256+tid; sw[m] = expf(sw[m]-mx)*winv; }

  // pass B: update rows + read scores  (rows L2-warm)
  for (int k=0;k<8;++k){
    int m = k*256 + tid;
    float* row = mb + (size_t)m*HSZ;
    float4 rr[16];
    #pragma unroll
    for (int j=0;j<16;++j) rr[j] = ((const float4*)row)[j];
    float ww = sw[m];
    #pragma unroll
    for (int i=0;i<16;++i){ int h=i*4;
      rr[i].x = rr[i].x*(1.f-ww*bc[192+h  ]) + ww*bc[256+h  ];
      rr[i].y = rr[i].y*(1.f-ww*bc[192+h+1]) + ww*bc[256+h+1];
      rr[i].z = rr[i].z*(1.f-ww*bc[192+h+2]) + ww*bc[256+h+2];
      rr[i].w = rr[i].w*(1.f-ww*bc[192+h+3]) + ww*bc[256+h+3];
    }
    #pragma unroll
    for (int j=0;j<16;++j) ((float4*)row)[j] = rr[j];
    float sum=0.f;
    #pragma unroll
    for (int i=0;i<16;++i) sum += rr[i].x+rr[i].y+rr[i].z+rr[i].w;
    float mu = sum*(1.f/64.f);
    float ssq=0.f;
    #pragma unroll
    for (int i=0;i<16;++i){ float dx=rr[i].x-mu,dy=rr[i].y-mu,dz=rr[i].z-mu,dw=rr[i].w-mu;
                            ssq+=dx*dx+dy*dy+dz*dz+dw*dw; }
    float rstd = rsqrtf(ssq*(1.f/64.f)+EPSF);
    float t0=0,t1=0,t2=0,t3=0;
    #pragma unroll
    for (int i=0;i<16;++i){ int h=i*4;
      float n0=(rr[i].x-mu)*rstd*bc[64+h  ]+bc[128+h  ];
      float n1=(rr[i].y-mu)*rstd*bc[64+h+1]+bc[128+h+1];
      float n2=(rr[i].z-mu)*rstd*bc[64+h+2]+bc[128+h+2];
      float n3=(rr[i].w-mu)*rstd*bc[64+h+3]+bc[128+h+3];
      t0 += n0*bc[320+h]    +n1*bc[320+h+1]    +n2*bc[320+h+2]    +n3*bc[320+h+3];
      t1 += n0*bc[384+h]    +n1*bc[384+h+1]    +n2*bc[384+h+2]    +n3*bc[384+h+3];
      t2 += n0*bc[448+h]    +n1*bc[448+h+1]    +n2*bc[448+h+2]    +n3*bc[448+h+3];
      t3 += n0*bc[512+h]    +n1*bc[512+h+1]    +n2*bc[512+h+2]    +n3*bc[512+h+3];
    }
    srd[m] = t0; srd[2048+m] = t1; srd[4096+m] = t2; srd[6144+m] = t3;
  }
  __syncthreads();
  // exact softmax per read head -> weights in srd
  #pragma unroll
  for (int n=0;n<RR;++n){
    float mxn = -3.4e38f;
    for (int k=0;k<8;++k) mxn = fmaxf(mxn, srd[n*2048+k*256+tid]);
    mxn = bmax(mxn, sred);
    float sen = 0.f;
    for (int k=0;k<8;++k) sen += expf(srd[n*2048+k*256+tid]-mxn);
    sen = bsum(sen, sred);
    float rinv = 1.f/sen;
    for (int k=0;k<8;++k){ int m=k*256+tid; srd[n*2048+m] = expf(srd[n*2048+m]-mxn)*rinv; }
  }
  __syncthreads();
  // pass C: rv gather (mem rows L2-warm; weights broadcast from LDS)
  int hs = tid & 63, wv = tid >> 6;
  float a0=0,a1=0,a2=0,a3=0;
  for (int m=wv; m<MM; m+=4){
    float v = mb[(size_t)m*HSZ + hs];
    a0 += srd[m]*v; a1 += srd[2048+m]*v; a2 += srd[4096+m]*v; a3 += srd[6144+m]*v;
  }
  sw[wv*256 + 0*64 + hs] = a0;
  sw[wv*256 + 1*64 + hs] = a1;
  sw[wv*256 + 2*64 + hs] = a2;
  sw[wv*256 + 3*64 + hs] = a3;
  __syncthreads();
  int n2 = tid>>6, h2 = tid&63;
  float rvv = sw[0*256+n2*64+h2]+sw[1*256+n2*64+h2]+sw[2*256+n2*64+h2]+sw[3*256+n2*64+h2];
  // tail: orow = LN(concat(hn, rv)); ci(t+1) = LN(concat(x_{t+1}, rv))
  float* row   = srd;          // 1280
  float* cirow = srd + 1280;   // 768
  row[HH+tid] = rvv;
  for (int i=tid;i<HH;i+=256) row[i] = p.hn[b*HH+i];
  __syncthreads();
  float s=0.f; for (int i=tid;i<PO;i+=256) s+=row[i];
  float mu = bsum(s,sred)*(1.f/PO);
  float ss=0.f; for (int i=tid;i<PO;i+=256){ float d=row[i]-mu; ss+=d*d; }
  float rstd = rsqrtf(bsum(ss,sred)*(1.f/PO)+EPSF);
  for (int i=tid;i<PO;i+=256)
    p.orow[b*PO+i] = (row[i]-mu)*rstd*p.ln_o_g[i]+p.ln_o_b[i];
  if (t+1 < LL) {
    for (int i=tid;i<CIN;i+=256)
      cirow[i] = (i<EE)? p.x_emb[(size_t)(b*LL+t+1)*EE+i] : row[HH+(i-EE)];
    __syncthreads();
    float s2=0.f; for (int i=tid;i<CIN;i+=256) s2+=cirow[i];
    float mu2 = bsum(s2,sred)*(1.f/CIN);
    float ss2=0.f; for (int i=tid;i<CIN;i+=256){ float d=cirow[i]-mu2; ss2+=d*d; }
    float rstd2 = rsqrtf(bsum(ss2,sred)*(1.f/CIN)+EPSF);
    for (int i=tid;i<CIN;i+=256)
      p.ci[b*CIN+i] = (cirow[i]-mu2)*rstd2*p.ln_in_g[i]+p.ln_in_b[i];
  }
}

__global__ __launch_bounds__(256, 1) void dnc_all(Params p) {
  __shared__ __align__(16) float smem[10816];
  __shared__ float sred[8];
  const int blk = blockIdx.x, tid = threadIdx.x;
  const int NB = gridDim.x;
  const int gsz = NB * 256;
  unsigned bnum = 0;

  // ---------------- P0: init ----------------
  {
    float4 z4 = make_float4(0.f,0.f,0.f,0.f);
    float4* m4 = (float4*)p.mem;
    int gidx = blk*256 + tid;
    for (int i = gidx; i < (BB*MM*HSZ)/4; i += gsz) m4[i] = z4;
    for (int i = gidx; i < (BB*HH)/4; i += gsz) { ((float4*)p.h)[i] = z4; ((float4*)p.c)[i] = z4; }
    for (int b = blk; b < BB; b += NB) {
      __syncthreads();
      for (int i = tid; i < CIN; i += 256)
        smem[i] = (i < EE) ? p.x_emb[(size_t)(b*LL)*EE + i] : 0.f;
      __syncthreads();
      float s = 0.f;
      for (int i = tid; i < CIN; i += 256) s += smem[i];
      float mu = bsum(s, sred) * (1.f/CIN);
      float ss = 0.f;
      for (int i = tid; i < CIN; i += 256) { float d = smem[i]-mu; ss += d*d; }
      float rstd = rsqrtf(bsum(ss, sred)*(1.f/CIN) + EPSF);
      for (int i = tid; i < CIN; i += 256)
        p.ci[b*CIN+i] = (smem[i]-mu)*rstd*p.ln_in_g[i] + p.ln_in_b[i];
    }
  }
  gbar(p.bar, (++bnum)*NB);

  for (int t = 0; t < LL; ++t) {
    const float* hprev = p.h + (t & 1) * (BB*HH);
    float* hnew = p.h + ((t+1) & 1) * (BB*HH);

    // ---------------- P1: gates GEMM + LSTM (256 tiles) ----------------
    for (int w = blk; w < 256; w += NB) {
      int cgp = w & 63, bg = w >> 6;
      int tb = tid >> 4, cq = tid & 15;
      int b0 = bg*16, j0 = cgp*16;
      float (*A)[68]  = (float(*)[68])smem;
      float (*Wt)[68] = (float(*)[68])(smem + 1088);
      float (*Gv)[68] = (float(*)[68])(smem + 5440);
      float acc0=0,acc1=0,acc2=0,acc3=0;
      int c0 = cq*4;
      for (int ph = 0; ph < 2; ++ph) {
        const float* Asrc = ph ? hprev : p.ci;
        const float* Wsrc = ph ? p.w_hh : p.w_ih;
        int K = ph ? HH : CIN;
        for (int k0 = 0; k0 < K; k0 += 64) {
          __syncthreads();
          { int ar = tid>>4, ac = (tid&15)<<2;
            float4 a4 = *(const float4*)&Asrc[(b0+ar)*K + k0 + ac];
            *(float4*)&A[ar][ac] = a4; }
          for (int i=0;i<4;++i){
            int idx2 = i*256+tid;
            int cc = idx2>>4, kq = (idx2&15)<<2;
            int gate = cc>>4, jl = cc&15;
            float4 w4 = *(const float4*)&Wsrc[(size_t)(gate*HH + j0 + jl)*K + k0 + kq];
            Wt[kq+0][cc]=w4.x; Wt[kq+1][cc]=w4.y; Wt[kq+2][cc]=w4.z; Wt[kq+3][cc]=w4.w;
          }
          __syncthreads();
          #pragma unroll
          for (int kk=0;kk<16;++kk){
            float4 a4 = *(const float4*)&A[tb][kk*4];
            float4 wv;
            wv=*(const float4*)&Wt[kk*4+0][c0]; acc0+=a4.x*wv.x; acc1+=a4.x*wv.y; acc2+=a4.x*wv.z; acc3+=a4.x*wv.w;
            wv=*(const float4*)&Wt[kk*4+1][c0]; acc0+=a4.y*wv.x; acc1+=a4.y*wv.y; acc2+=a4.y*wv.z; acc3+=a4.y*wv.w;
            wv=*(const float4*)&Wt[kk*4+2][c0]; acc0+=a4.z*wv.x; acc1+=a4.z*wv.y; acc2+=a4.z*wv.z; acc3+=a4.z*wv.w;
            wv=*(const float4*)&Wt[kk*4+3][c0]; acc0+=a4.w*wv.x; acc1+=a4.w*wv.y; acc2+=a4.w*wv.z; acc3+=a4.w*wv.w;
          }
        }
      }
      { int gate = c0>>4; int r = gate*HH + j0 + (c0&15);
        acc0 += p.b_ih[r]+p.b_hh[r];     acc1 += p.b_ih[r+1]+p.b_hh[r+1];
        acc2 += p.b_ih[r+2]+p.b_hh[r+2]; acc3 += p.b_ih[r+3]+p.b_hh[r+3]; }
      Gv[tb][c0]=acc0; Gv[tb][c0+1]=acc1; Gv[tb][c0+2]=acc2; Gv[tb][c0+3]=acc3;
      __syncthreads();
      { int jl = cq;
        float gi=Gv[tb][jl], gf=Gv[tb][16+jl], gg=Gv[tb][32+jl], go=Gv[tb][48+jl];
        int idx3 = (b0+tb)*HH + j0 + jl;
        float cold = p.c[idx3];
        float cn = sigm(gf)*cold + sigm(gi)*tanhf(gg);
        p.c[idx3] = cn;
        hnew[idx3] = sigm(go)*tanhf(cn);
      }
      __syncthreads();
    }
    gbar(p.bar, (++bnum)*NB);

    // ---------------- P2: hn LN + heads (256 tiles) ----------------
    for (int w = blk; w < 256; w += NB) {
      int b = w >> 2, q = w & 3;
      float* hrow = smem;          // 1024
      float* raw  = smem + 1024;   // up to 129
      __syncthreads();
      ((float4*)hrow)[tid] = ((const float4*)&hnew[b*HH])[tid];
      __syncthreads();
      float s=0.f; for (int i=tid;i<HH;i+=256) s += hrow[i];
      float mu = bsum(s,sred)*(1.f/HH);
      float ss=0.f; for (int i=tid;i<HH;i+=256){ float d=hrow[i]-mu; ss+=d*d; }
      float rstd = rsqrtf(bsum(ss,sred)*(1.f/HH)+EPSF);
      for (int i=tid;i<HH;i+=256){
        float v=(hrow[i]-mu)*rstd*p.ln_c_g[i]+p.ln_c_b[i];
        hrow[i]=v;
        if (q==0) p.hn[b*HH+i]=v;
      }
      __syncthreads();
      int base = (q==0)?0 : (q==1)?128 : (q==2)?256 : 385;
      int cnt  = (q==2)?129 : (q==3)?64 : 128;
      if (tid < cnt) {
        int gr = base + tid;
        const float* wrow; float bias;
        if (gr < 256)      { wrow = p.w_rk + (size_t)gr*HH;        bias = p.b_rk[gr]; }
        else if (gr < 320) { wrow = p.w_wk + (size_t)(gr-256)*HH;  bias = p.b_wk[gr-256]; }
        else if (gr == 320){ wrow = p.w_ws;                        bias = p.b_ws[0]; }
        else if (gr < 385) { wrow = p.w_er + (size_t)(gr-321)*HH;  bias = p.b_er[gr-321]; }
        else               { wrow = p.w_ad + (size_t)(gr-385)*HH;  bias = p.b_ad[gr-385]; }
        float acc = bias;
        #pragma unroll 8
        for (int k=0;k<HH;k+=4){
          float4 w4 = *(const float4*)&wrow[k];
          acc += w4.x*hrow[k]+w4.y*hrow[k+1]+w4.z*hrow[k+2]+w4.w*hrow[k+3];
        }
        raw[tid] = acc;
      }
      __syncthreads();
      if (q < 2) {
        if (tid < 128) {
          int g2 = tid>>6, l = tid&63;
          int head = q*2 + g2;
          float v = raw[g2*64 + l];
          float sv=v; for(int o=32;o>0;o>>=1) sv += __shfl_xor(sv,o,64);
          float m2 = sv*(1.f/64.f);
          float d = v-m2; float sq=d*d;
          for(int o=32;o>0;o>>=1) sq += __shfl_xor(sq,o,64);
          float rs = rsqrtf(sq*(1.f/64.f)+EPSF);
          p.rkn[(b*RR+head)*HSZ + l] = d*rs*p.ln_rk_g[l] + p.ln_rk_b[l];
        }
      } else if (q == 2) {
        if (tid < 64) {
          float v = raw[tid];
          float sv=v; for(int o=32;o>0;o>>=1) sv += __shfl_xor(sv,o,64);
          float m2 = sv*(1.f/64.f);
          float d=v-m2; float sq=d*d;
          for(int o=32;o>0;o>>=1) sq += __shfl_xor(sq,o,64);
          float rs = rsqrtf(sq*(1.f/64.f)+EPSF);
          p.wkn[b*HSZ+tid] = d*rs*p.ln_wk_g[tid] + p.ln_wk_b[tid];
          p.ers[b*HSZ+tid] = sigm(raw[65+tid]);
          if (tid==0) p.wss[b] = sigm(raw[64]);
        }
      } else {
        if (tid < 64) p.ads[b*HSZ+tid] = tanhf(raw[tid]);
      }
      __syncthreads();
    }
    gbar(p.bar, (++bnum)*NB);

    // ---------------- P34: per-b memory pipeline (64 tiles) + logits(t-1) (64 tiles) ----------------
    for (int w = blk; w < 128; w += NB) {
      __syncthreads();
      if (w < 64) {
        mem_phase(p, w, tid, t, smem, sred);
      } else if (t > 0) {
        logits_tile(p, w - 64, tid, t-1, smem);
      }
      __syncthreads();
    }
    gbar(p.bar, (++bnum)*NB);
  }

  // ---------------- finale: logits(255) + ht/ct ----------------
  for (int w = blk; w < 64; w += NB) logits_tile(p, w, tid, LL-1, smem);
  {
    int gidx = blk*256 + tid;
    for (int i = gidx; i < (BB*HH)/4; i += gsz) {
      ((float4*)p.ht)[i] = ((const float4*)p.h)[i];
      ((float4*)p.ct)[i] = ((const float4*)p.c)[i];
    }
  }
}

extern "C" void kernel_launch(void* const* d_in, const int* in_sizes, int n_in,
                              void* d_out, int out_size, void* d_ws, size_t ws_size,
                              hipStream_t stream) {
  Params prm;
  prm.x_emb  = (const float*)d_in[0];
  prm.ln_in_g= (const float*)d_in[1];
  prm.ln_in_b= (const float*)d_in[2];
  prm.w_ih   = (const float*)d_in[3];
  prm.w_hh   = (const float*)d_in[4];
  prm.b_ih   = (const float*)d_in[5];
  prm.b_hh   = (const float*)d_in[6];
  prm.ln_c_g = (const float*)d_in[7];
  prm.ln_c_b = (const float*)d_in[8];
  prm.w_rk   = (const float*)d_in[9];
  prm.b_rk   = (const float*)d_in[10];
  prm.w_wk   = (const float*)d_in[11];
  prm.b_wk   = (const float*)d_in[12];
  prm.w_ws   = (const float*)d_in[13];
  prm.b_ws   = (const float*)d_in[14];
  prm.w_er   = (const float*)d_in[15];
  prm.b_er   = (const float*)d_in[16];
  prm.w_ad   = (const float*)d_in[17];
  prm.b_ad   = (const float*)d_in[18];
  prm.ln_rk_g= (const float*)d_in[19];
  prm.ln_rk_b= (const float*)d_in[20];
  prm.ln_wk_g= (const float*)d_in[21];
  prm.ln_wk_b= (const float*)d_in[22];
  prm.ln_m_g = (const float*)d_in[23];
  prm.ln_m_b = (const float*)d_in[24];
  prm.ln_o_g = (const float*)d_in[25];
  prm.ln_o_b = (const float*)d_in[26];
  prm.w_p    = (const float*)d_in[27];
  prm.b_p    = (const float*)d_in[28];

  float* out = (float*)d_out;
  prm.y   = out + OUT_Y;
  prm.mem = out + OUT_MEM;
  prm.ht  = out + OUT_HT;
  prm.ct  = out + OUT_CT;

  // barrier counter in first bytes of d_ws; re-zeroed every call (capture-legal)
  prm.bar = (unsigned*)d_ws;
  hipMemsetAsync(d_ws, 0, 64, stream);

  float* ws = (float*)((char*)d_ws + 256);
  size_t o = 0;
  prm.h     = ws + o; o += 2*BB*HH;
  prm.c     = ws + o; o += BB*HH;
  prm.hn    = ws + o; o += BB*HH;
  prm.ci    = ws + o; o += BB*CIN;
  prm.rkn   = ws + o; o += BB*RR*HSZ;
  prm.wkn   = ws + o; o += BB*HSZ;
  prm.ers   = ws + o; o += BB*HSZ;
  prm.ads   = ws + o; o += BB*HSZ;
  prm.wss   = ws + o; o += BB;
  prm.orow  = ws + o; o += BB*PO;

  // size grid to guaranteed-co-resident block count
  int dev = 0;
  hipGetDevice(&dev);
  int ncu = 0;
  hipDeviceGetAttribute(&ncu, hipDeviceAttributeMultiprocessorCount, dev);
  if (ncu <= 0) ncu = 64;
  int nb = ncu < NBLK ? ncu : NBLK;
  int nbp = 1;
  while (nbp * 2 <= nb) nbp *= 2;

  dnc_all<<<dim3(nbp), dim3(256), 0, stream>>>(prm);
}

// Round 6
// 55624.841 us; speedup vs baseline: 2.5238x; 1.4675x over previous
//
#include <hip/hip_runtime.h>
#include <math.h>

#define BB 64
#define LL 256
#define EE 512
#define HH 1024
#define MM 2048
#define HSZ 64
#define RR 4
#define CIN 768
#define PO 1280
#define OO 1024
#define EPSF 1e-5f
#define NBLK 256

// ---- d_out layout (float offsets) ----
#define OUT_Y    0
#define OUT_MEM  (BB * LL * OO)
#define OUT_HT   (OUT_MEM + BB * MM * HSZ)
#define OUT_CT   (OUT_HT + BB * HH)

struct Params {
  const float *x_emb, *ln_in_g, *ln_in_b, *w_ih, *w_hh, *b_ih, *b_hh;
  const float *ln_c_g, *ln_c_b, *w_rk, *b_rk, *w_wk, *b_wk, *w_ws, *b_ws;
  const float *w_er, *b_er, *w_ad, *b_ad, *ln_rk_g, *ln_rk_b, *ln_wk_g, *ln_wk_b;
  const float *ln_m_g, *ln_m_b, *ln_o_g, *ln_o_b, *w_p, *b_p;
  float *y, *mem, *ht, *ct;
  float *h, *c, *hn, *ci, *rkn, *wkn, *ers, *ads, *wss, *orow;
  unsigned *bar;
};

__device__ __forceinline__ float sigm(float x){ return 1.f/(1.f+expf(-x)); }

// device-coherent (agent-scope) accessors for CROSS-BLOCK tensors only.
// These are coherent at the device point (L3) — no L2 flush/invalidate needed.
__device__ __forceinline__ float dload(const float* p){
  return __hip_atomic_load(p, __ATOMIC_RELAXED, __HIP_MEMORY_SCOPE_AGENT);
}
__device__ __forceinline__ void dstore(float* p, float v){
  __hip_atomic_store(p, v, __ATOMIC_RELAXED, __HIP_MEMORY_SCOPE_AGENT);
}

// Grid barrier WITHOUT threadfence: producer data goes through agent-scope
// stores (above); s_waitcnt vmcnt(0) guarantees they reached the coherence
// point before the flag increment. No L2 writeback/invalidate => caches stay hot.
__device__ __forceinline__ void gbar(unsigned* bar, unsigned target) {
  __syncthreads();
  if (threadIdx.x == 0) {
    asm volatile("s_waitcnt vmcnt(0)" ::: "memory");
    __hip_atomic_fetch_add(bar, 1u, __ATOMIC_RELAXED, __HIP_MEMORY_SCOPE_AGENT);
    while (__hip_atomic_load(bar, __ATOMIC_RELAXED, __HIP_MEMORY_SCOPE_AGENT) < target) {
      __builtin_amdgcn_s_sleep(8);
    }
    asm volatile("" ::: "memory");
  }
  __syncthreads();
}

__device__ __forceinline__ float bsum(float v, volatile float* red){
  __syncthreads();
  for (int o=32;o>0;o>>=1) v += __shfl_down(v,o,64);
  int w = threadIdx.x>>6;
  if ((threadIdx.x&63)==0) red[w]=v;
  __syncthreads();
  return red[0]+red[1]+red[2]+red[3];
}
__device__ __forceinline__ float bmax(float v, volatile float* red){
  __syncthreads();
  for (int o=32;o>0;o>>=1) v = fmaxf(v,__shfl_down(v,o,64));
  int w = threadIdx.x>>6;
  if ((threadIdx.x&63)==0) red[w]=v;
  __syncthreads();
  return fmaxf(fmaxf(red[0],red[1]),fmaxf(red[2],red[3]));
}

// LN stats + dot(LN(row), wk) for a 64-wide row held as 16 float4 in regs
__device__ __forceinline__ float row_score(const float4* v, const float* wk,
                                           const float* g, const float* bt){
  float sum=0.f;
  #pragma unroll
  for (int i=0;i<16;++i) sum += v[i].x+v[i].y+v[i].z+v[i].w;
  float mu = sum*(1.f/64.f);
  float ssq=0.f;
  #pragma unroll
  for (int i=0;i<16;++i){ float dx=v[i].x-mu,dy=v[i].y-mu,dz=v[i].z-mu,dw=v[i].w-mu;
                          ssq+=dx*dx+dy*dy+dz*dz+dw*dw; }
  float rstd = rsqrtf(ssq*(1.f/64.f)+EPSF);
  float sc=0.f;
  #pragma unroll
  for (int i=0;i<16;++i){ int h=i*4;
    sc += ((v[i].x-mu)*rstd*g[h  ]+bt[h  ])*wk[h  ];
    sc += ((v[i].y-mu)*rstd*g[h+1]+bt[h+1])*wk[h+1];
    sc += ((v[i].z-mu)*rstd*g[h+2]+bt[h+2])*wk[h+2];
    sc += ((v[i].w-mu)*rstd*g[h+3]+bt[h+3])*wk[h+3];
  }
  return sc;
}

__device__ void logits_tile(const Params& p, int w, int tid, int tprev, float* smem){
  int cgl = w & 15, bg = w >> 4;
  int tb = tid >> 4, cq = tid & 15;
  int b0 = bg*16, col0 = cgl*64;
  float (*A)[68]  = (float(*)[68])smem;
  float (*Wt)[68] = (float(*)[68])(smem+1088);
  float acc0=0,acc1=0,acc2=0,acc3=0;
  int c0 = cq*4;
  for (int k0=0;k0<PO;k0+=64){
    __syncthreads();
    { int ar=tid>>4, ac=(tid&15)<<2;
      const float* ap = &p.orow[(b0+ar)*PO + k0 + ac];
      float a0=dload(ap), a1=dload(ap+1), a2=dload(ap+2), a3=dload(ap+3);
      A[ar][ac]=a0; A[ar][ac+1]=a1; A[ar][ac+2]=a2; A[ar][ac+3]=a3; }
    for (int i=0;i<4;++i){
      int idx=i*256+tid; int cc=idx>>4; int kq=(idx&15)<<2;
      float4 w4 = *(const float4*)&p.w_p[(size_t)(col0+cc)*PO + k0 + kq];
      Wt[kq+0][cc]=w4.x; Wt[kq+1][cc]=w4.y; Wt[kq+2][cc]=w4.z; Wt[kq+3][cc]=w4.w;
    }
    __syncthreads();
    #pragma unroll
    for (int kk=0;kk<16;++kk){
      float4 a4 = *(const float4*)&A[tb][kk*4];
      float4 wv;
      wv=*(const float4*)&Wt[kk*4+0][c0]; acc0+=a4.x*wv.x; acc1+=a4.x*wv.y; acc2+=a4.x*wv.z; acc3+=a4.x*wv.w;
      wv=*(const float4*)&Wt[kk*4+1][c0]; acc0+=a4.y*wv.x; acc1+=a4.y*wv.y; acc2+=a4.y*wv.z; acc3+=a4.y*wv.w;
      wv=*(const float4*)&Wt[kk*4+2][c0]; acc0+=a4.z*wv.x; acc1+=a4.z*wv.y; acc2+=a4.z*wv.z; acc3+=a4.z*wv.w;
      wv=*(const float4*)&Wt[kk*4+3][c0]; acc0+=a4.w*wv.x; acc1+=a4.w*wv.y; acc2+=a4.w*wv.z; acc3+=a4.w*wv.w;
    }
  }
  int col = col0 + c0;
  float4 o;
  o.x=acc0+p.b_p[col]; o.y=acc1+p.b_p[col+1]; o.z=acc2+p.b_p[col+2]; o.w=acc3+p.b_p[col+3];
  *(float4*)&p.y[(size_t)((b0+tb)*LL + tprev)*OO + col] = o;
}

// per-b memory pipeline, block-local (mem slice owned by this block forever).
__device__ void mem_phase(const Params& p, int b, int tid, int t, float* smem, float* sred){
  float* bc  = smem;          // [576] broadcasts
  float* sw  = smem + 576;    // [2048] write scores -> weights -> rv partials
  float* srd = smem + 2624;   // [4*2048] read scores -> weights; then row/cirow
  if (tid < 64) {
    bc[tid]     = dload(&p.wkn[b*HSZ+tid]);
    bc[64+tid]  = p.ln_m_g[tid];
    bc[128+tid] = p.ln_m_b[tid];
    bc[192+tid] = dload(&p.ers[b*HSZ+tid]);
    bc[256+tid] = dload(&p.ads[b*HSZ+tid]);
  }
  bc[320+tid] = dload(&p.rkn[b*RR*HSZ + tid]);
  __syncthreads();
  float wstr = dload(&p.wss[b]);
  float* mb = p.mem + (size_t)b*MM*HSZ;

  // pass A: write scores
  for (int k=0;k<8;++k){
    int m = k*256 + tid;
    const float4* row = (const float4*)(mb + (size_t)m*HSZ);
    float4 rr[16];
    #pragma unroll
    for (int j=0;j<16;++j) rr[j] = row[j];
    sw[m] = row_score(rr, bc, bc+64, bc+128);
  }
  __syncthreads();
  float mx = -3.4e38f;
  for (int k=0;k<8;++k) mx = fmaxf(mx, sw[k*256+tid]);
  mx = bmax(mx, sred);
  float se = 0.f;
  for (int k=0;k<8;++k) se += expf(sw[k*256+tid]-mx);
  se = bsum(se, sred);
  float winv = wstr / se;
  for (int k=0;k<8;++k){ int m=k*256+tid; sw[m] = expf(sw[m]-mx)*winv; }

  // pass B: update rows + read scores (rows L2-warm, never flushed now)
  for (int k=0;k<8;++k){
    int m = k*256 + tid;
    float* row = mb + (size_t)m*HSZ;
    float4 rr[16];
    #pragma unroll
    for (int j=0;j<16;++j) rr[j] = ((const float4*)row)[j];
    float ww = sw[m];
    #pragma unroll
    for (int i=0;i<16;++i){ int h=i*4;
      rr[i].x = rr[i].x*(1.f-ww*bc[192+h  ]) + ww*bc[256+h  ];
      rr[i].y = rr[i].y*(1.f-ww*bc[192+h+1]) + ww*bc[256+h+1];
      rr[i].z = rr[i].z*(1.f-ww*bc[192+h+2]) + ww*bc[256+h+2];
      rr[i].w = rr[i].w*(1.f-ww*bc[192+h+3]) + ww*bc[256+h+3];
    }
    #pragma unroll
    for (int j=0;j<16;++j) ((float4*)row)[j] = rr[j];
    float sum=0.f;
    #pragma unroll
    for (int i=0;i<16;++i) sum += rr[i].x+rr[i].y+rr[i].z+rr[i].w;
    float mu = sum*(1.f/64.f);
    float ssq=0.f;
    #pragma unroll
    for (int i=0;i<16;++i){ float dx=rr[i].x-mu,dy=rr[i].y-mu,dz=rr[i].z-mu,dw=rr[i].w-mu;
                            ssq+=dx*dx+dy*dy+dz*dz+dw*dw; }
    float rstd = rsqrtf(ssq*(1.f/64.f)+EPSF);
    float t0=0,t1=0,t2=0,t3=0;
    #pragma unroll
    for (int i=0;i<16;++i){ int h=i*4;
      float n0=(rr[i].x-mu)*rstd*bc[64+h  ]+bc[128+h  ];
      float n1=(rr[i].y-mu)*rstd*bc[64+h+1]+bc[128+h+1];
      float n2=(rr[i].z-mu)*rstd*bc[64+h+2]+bc[128+h+2];
      float n3=(rr[i].w-mu)*rstd*bc[64+h+3]+bc[128+h+3];
      t0 += n0*bc[320+h]+n1*bc[320+h+1]+n2*bc[320+h+2]+n3*bc[320+h+3];
      t1 += n0*bc[384+h]+n1*bc[384+h+1]+n2*bc[384+h+2]+n3*bc[384+h+3];
      t2 += n0*bc[448+h]+n1*bc[448+h+1]+n2*bc[448+h+2]+n3*bc[448+h+3];
      t3 += n0*bc[512+h]+n1*bc[512+h+1]+n2*bc[512+h+2]+n3*bc[512+h+3];
    }
    srd[m] = t0; srd[2048+m] = t1; srd[4096+m] = t2; srd[6144+m] = t3;
  }
  __syncthreads();
  #pragma unroll
  for (int n=0;n<RR;++n){
    float mxn = -3.4e38f;
    for (int k=0;k<8;++k) mxn = fmaxf(mxn, srd[n*2048+k*256+tid]);
    mxn = bmax(mxn, sred);
    float sen = 0.f;
    for (int k=0;k<8;++k) sen += expf(srd[n*2048+k*256+tid]-mxn);
    sen = bsum(sen, sred);
    float rinv = 1.f/sen;
    for (int k=0;k<8;++k){ int m=k*256+tid; srd[n*2048+m] = expf(srd[n*2048+m]-mxn)*rinv; }
  }
  __syncthreads();
  // pass C: rv gather — 8 independent loads in flight per batch (latency fix)
  int hs = tid & 63, wv = tid >> 6;
  float a0=0,a1=0,a2=0,a3=0;
  for (int mb8=0; mb8<MM; mb8+=32){
    float v[8];
    #pragma unroll
    for (int j=0;j<8;++j) v[j] = mb[(size_t)(mb8 + wv + 4*j)*HSZ + hs];
    #pragma unroll
    for (int j=0;j<8;++j){
      int m = mb8 + wv + 4*j;
      a0 += srd[m]*v[j]; a1 += srd[2048+m]*v[j]; a2 += srd[4096+m]*v[j]; a3 += srd[6144+m]*v[j];
    }
  }
  sw[wv*256 + 0*64 + hs] = a0;
  sw[wv*256 + 1*64 + hs] = a1;
  sw[wv*256 + 2*64 + hs] = a2;
  sw[wv*256 + 3*64 + hs] = a3;
  __syncthreads();
  int n2 = tid>>6, h2 = tid&63;
  float rvv = sw[0*256+n2*64+h2]+sw[1*256+n2*64+h2]+sw[2*256+n2*64+h2]+sw[3*256+n2*64+h2];
  // tail: orow = LN(concat(hn, rv)); ci(t+1) = LN(concat(x_{t+1}, rv))
  float* row   = srd;          // 1280
  float* cirow = srd + 1280;   // 768
  row[HH+tid] = rvv;
  for (int i=tid;i<HH;i+=256) row[i] = dload(&p.hn[b*HH+i]);
  __syncthreads();
  float s=0.f; for (int i=tid;i<PO;i+=256) s+=row[i];
  float mu = bsum(s,sred)*(1.f/PO);
  float ss=0.f; for (int i=tid;i<PO;i+=256){ float d=row[i]-mu; ss+=d*d; }
  float rstd = rsqrtf(bsum(ss,sred)*(1.f/PO)+EPSF);
  for (int i=tid;i<PO;i+=256)
    dstore(&p.orow[b*PO+i], (row[i]-mu)*rstd*p.ln_o_g[i]+p.ln_o_b[i]);
  if (t+1 < LL) {
    for (int i=tid;i<CIN;i+=256)
      cirow[i] = (i<EE)? p.x_emb[(size_t)(b*LL+t+1)*EE+i] : row[HH+(i-EE)];
    __syncthreads();
    float s2=0.f; for (int i=tid;i<CIN;i+=256) s2+=cirow[i];
    float mu2 = bsum(s2,sred)*(1.f/CIN);
    float ss2=0.f; for (int i=tid;i<CIN;i+=256){ float d=cirow[i]-mu2; ss2+=d*d; }
    float rstd2 = rsqrtf(bsum(ss2,sred)*(1.f/CIN)+EPSF);
    for (int i=tid;i<CIN;i+=256)
      dstore(&p.ci[b*CIN+i], (cirow[i]-mu2)*rstd2*p.ln_in_g[i]+p.ln_in_b[i]);
  }
}

__global__ __launch_bounds__(256, 1) void dnc_all(Params p) {
  __shared__ __align__(16) float smem[10816];
  __shared__ float sred[8];
  const int blk = blockIdx.x, tid = threadIdx.x;
  const int NB = gridDim.x;
  unsigned bnum = 0;

  // ---------------- P0: init (owner blocks only; h/ci via agent stores) ----------------
  {
    // mem slice b is owned by block b%NB forever: zero it locally (cached path)
    for (int b = blk; b < BB; b += NB) {
      float4 z4 = make_float4(0.f,0.f,0.f,0.f);
      float4* m4 = (float4*)(p.mem + (size_t)b*MM*HSZ);
      for (int i = tid; i < (MM*HSZ)/4; i += 256) m4[i] = z4;
    }
    // h(t=0) zeros — cross-block, agent stores
    { int gidx = blk*256 + tid;
      for (int i = gidx; i < BB*HH; i += NB*256) dstore(&p.h[i], 0.f); }
    // ci(t=0) = LN(concat(x_0, 0)) — cross-block, agent stores
    for (int b = blk; b < BB; b += NB) {
      __syncthreads();
      for (int i = tid; i < CIN; i += 256)
        smem[i] = (i < EE) ? p.x_emb[(size_t)(b*LL)*EE + i] : 0.f;
      __syncthreads();
      float s = 0.f;
      for (int i = tid; i < CIN; i += 256) s += smem[i];
      float mu = bsum(s, sred) * (1.f/CIN);
      float ss = 0.f;
      for (int i = tid; i < CIN; i += 256) { float d = smem[i]-mu; ss += d*d; }
      float rstd = rsqrtf(bsum(ss, sred)*(1.f/CIN) + EPSF);
      for (int i = tid; i < CIN; i += 256)
        dstore(&p.ci[b*CIN+i], (smem[i]-mu)*rstd*p.ln_in_g[i] + p.ln_in_b[i]);
    }
  }
  gbar(p.bar, (++bnum)*NB);

  for (int t = 0; t < LL; ++t) {
    float* hprev = p.h + (t & 1) * (BB*HH);
    float* hnew = p.h + ((t+1) & 1) * (BB*HH);

    // ---------------- P1: gates GEMM + LSTM (256 tiles; c is tile-local) ----------------
    for (int w = blk; w < 256; w += NB) {
      int cgp = w & 63, bg = w >> 6;
      int tb = tid >> 4, cq = tid & 15;
      int b0 = bg*16, j0 = cgp*16;
      float (*A)[68]  = (float(*)[68])smem;
      float (*Wt)[68] = (float(*)[68])(smem + 1088);
      float (*Gv)[68] = (float(*)[68])(smem + 5440);
      float acc0=0,acc1=0,acc2=0,acc3=0;
      int c0 = cq*4;
      for (int ph = 0; ph < 2; ++ph) {
        const float* Asrc = ph ? hprev : p.ci;
        const float* Wsrc = ph ? p.w_hh : p.w_ih;
        int K = ph ? HH : CIN;
        for (int k0 = 0; k0 < K; k0 += 64) {
          __syncthreads();
          { int ar = tid>>4, ac = (tid&15)<<2;
            const float* ap = &Asrc[(b0+ar)*K + k0 + ac];
            float a0=dload(ap), a1=dload(ap+1), a2=dload(ap+2), a3=dload(ap+3);
            A[ar][ac]=a0; A[ar][ac+1]=a1; A[ar][ac+2]=a2; A[ar][ac+3]=a3; }
          for (int i=0;i<4;++i){
            int idx2 = i*256+tid;
            int cc = idx2>>4, kq = (idx2&15)<<2;
            int gate = cc>>4, jl = cc&15;
            float4 w4 = *(const float4*)&Wsrc[(size_t)(gate*HH + j0 + jl)*K + k0 + kq];
            Wt[kq+0][cc]=w4.x; Wt[kq+1][cc]=w4.y; Wt[kq+2][cc]=w4.z; Wt[kq+3][cc]=w4.w;
          }
          __syncthreads();
          #pragma unroll
          for (int kk=0;kk<16;++kk){
            float4 a4 = *(const float4*)&A[tb][kk*4];
            float4 wv;
            wv=*(const float4*)&Wt[kk*4+0][c0]; acc0+=a4.x*wv.x; acc1+=a4.x*wv.y; acc2+=a4.x*wv.z; acc3+=a4.x*wv.w;
            wv=*(const float4*)&Wt[kk*4+1][c0]; acc0+=a4.y*wv.x; acc1+=a4.y*wv.y; acc2+=a4.y*wv.z; acc3+=a4.y*wv.w;
            wv=*(const float4*)&Wt[kk*4+2][c0]; acc0+=a4.z*wv.x; acc1+=a4.z*wv.y; acc2+=a4.z*wv.z; acc3+=a4.z*wv.w;
            wv=*(const float4*)&Wt[kk*4+3][c0]; acc0+=a4.w*wv.x; acc1+=a4.w*wv.y; acc2+=a4.w*wv.z; acc3+=a4.w*wv.w;
          }
        }
      }
      { int gate = c0>>4; int r = gate*HH + j0 + (c0&15);
        acc0 += p.b_ih[r]+p.b_hh[r];     acc1 += p.b_ih[r+1]+p.b_hh[r+1];
        acc2 += p.b_ih[r+2]+p.b_hh[r+2]; acc3 += p.b_ih[r+3]+p.b_hh[r+3]; }
      Gv[tb][c0]=acc0; Gv[tb][c0+1]=acc1; Gv[tb][c0+2]=acc2; Gv[tb][c0+3]=acc3;
      __syncthreads();
      { int jl = cq;
        float gi=Gv[tb][jl], gf=Gv[tb][16+jl], gg=Gv[tb][32+jl], go=Gv[tb][48+jl];
        int idx3 = (b0+tb)*HH + j0 + jl;
        float cold = (t==0) ? 0.f : p.c[idx3];     // c is tile-local: cached path
        float cn = sigm(gf)*cold + sigm(gi)*tanhf(gg);
        float hv = sigm(go)*tanhf(cn);
        p.c[idx3] = cn;
        dstore(&hnew[idx3], hv);                    // cross-block: agent
        if (t == LL-1) { p.ht[idx3] = hv; p.ct[idx3] = cn; }   // outputs (host-read)
      }
      __syncthreads();
    }
    gbar(p.bar, (++bnum)*NB);

    // ---------------- P2: hn LN + heads (256 tiles) ----------------
    for (int w = blk; w < 256; w += NB) {
      int b = w >> 2, q = w & 3;
      float* hrow = smem;          // 1024
      float* raw  = smem + 1024;   // up to 129
      __syncthreads();
      { int i0 = tid*4;
        const float* hp = &hnew[b*HH + i0];
        float a0=dload(hp), a1=dload(hp+1), a2=dload(hp+2), a3=dload(hp+3);
        hrow[i0]=a0; hrow[i0+1]=a1; hrow[i0+2]=a2; hrow[i0+3]=a3; }
      __syncthreads();
      float s=0.f; for (int i=tid;i<HH;i+=256) s += hrow[i];
      float mu = bsum(s,sred)*(1.f/HH);
      float ss=0.f; for (int i=tid;i<HH;i+=256){ float d=hrow[i]-mu; ss+=d*d; }
      float rstd = rsqrtf(bsum(ss,sred)*(1.f/HH)+EPSF);
      for (int i=tid;i<HH;i+=256){
        float v=(hrow[i]-mu)*rstd*p.ln_c_g[i]+p.ln_c_b[i];
        hrow[i]=v;
        if (q==0) dstore(&p.hn[b*HH+i], v);
      }
      __syncthreads();
      int base = (q==0)?0 : (q==1)?128 : (q==2)?256 : 385;
      int cnt  = (q==2)?129 : (q==3)?64 : 128;
      if (tid < cnt) {
        int gr = base + tid;
        const float* wrow; float bias;
        if (gr < 256)      { wrow = p.w_rk + (size_t)gr*HH;        bias = p.b_rk[gr]; }
        else if (gr < 320) { wrow = p.w_wk + (size_t)(gr-256)*HH;  bias = p.b_wk[gr-256]; }
        else if (gr == 320){ wrow = p.w_ws;                        bias = p.b_ws[0]; }
        else if (gr < 385) { wrow = p.w_er + (size_t)(gr-321)*HH;  bias = p.b_er[gr-321]; }
        else               { wrow = p.w_ad + (size_t)(gr-385)*HH;  bias = p.b_ad[gr-385]; }
        float acc = bias;
        #pragma unroll 8
        for (int k=0;k<HH;k+=4){
          float4 w4 = *(const float4*)&wrow[k];
          acc += w4.x*hrow[k]+w4.y*hrow[k+1]+w4.z*hrow[k+2]+w4.w*hrow[k+3];
        }
        raw[tid] = acc;
      }
      __syncthreads();
      if (q < 2) {
        if (tid < 128) {
          int g2 = tid>>6, l = tid&63;
          int head = q*2 + g2;
          float v = raw[g2*64 + l];
          float sv=v; for(int o=32;o>0;o>>=1) sv += __shfl_xor(sv,o,64);
          float m2 = sv*(1.f/64.f);
          float d = v-m2; float sq=d*d;
          for(int o=32;o>0;o>>=1) sq += __shfl_xor(sq,o,64);
          float rs = rsqrtf(sq*(1.f/64.f)+EPSF);
          dstore(&p.rkn[(b*RR+head)*HSZ + l], d*rs*p.ln_rk_g[l] + p.ln_rk_b[l]);
        }
      } else if (q == 2) {
        if (tid < 64) {
          float v = raw[tid];
          float sv=v; for(int o=32;o>0;o>>=1) sv += __shfl_xor(sv,o,64);
          float m2 = sv*(1.f/64.f);
          float d=v-m2; float sq=d*d;
          for(int o=32;o>0;o>>=1) sq += __shfl_xor(sq,o,64);
          float rs = rsqrtf(sq*(1.f/64.f)+EPSF);
          dstore(&p.wkn[b*HSZ+tid], d*rs*p.ln_wk_g[tid] + p.ln_wk_b[tid]);
          dstore(&p.ers[b*HSZ+tid], sigm(raw[65+tid]));
          if (tid==0) dstore(&p.wss[b], sigm(raw[64]));
        }
      } else {
        if (tid < 64) dstore(&p.ads[b*HSZ+tid], tanhf(raw[tid]));
      }
      __syncthreads();
    }
    gbar(p.bar, (++bnum)*NB);

    // ---------------- P34: mem pipeline (64) + logits(t-1) (64) ----------------
    for (int w = blk; w < 128; w += NB) {
      __syncthreads();
      if (w < 64) {
        mem_phase(p, w, tid, t, smem, sred);
      } else if (t > 0) {
        logits_tile(p, w - 64, tid, t-1, smem);
      }
      __syncthreads();
    }
    gbar(p.bar, (++bnum)*NB);
  }

  // ---------------- finale: logits(255) ----------------
  for (int w = blk; w < 64; w += NB) logits_tile(p, w, tid, LL-1, smem);
}

extern "C" void kernel_launch(void* const* d_in, const int* in_sizes, int n_in,
                              void* d_out, int out_size, void* d_ws, size_t ws_size,
                              hipStream_t stream) {
  Params prm;
  prm.x_emb  = (const float*)d_in[0];
  prm.ln_in_g= (const float*)d_in[1];
  prm.ln_in_b= (const float*)d_in[2];
  prm.w_ih   = (const float*)d_in[3];
  prm.w_hh   = (const float*)d_in[4];
  prm.b_ih   = (const float*)d_in[5];
  prm.b_hh   = (const float*)d_in[6];
  prm.ln_c_g = (const float*)d_in[7];
  prm.ln_c_b = (const float*)d_in[8];
  prm.w_rk   = (const float*)d_in[9];
  prm.b_rk   = (const float*)d_in[10];
  prm.w_wk   = (const float*)d_in[11];
  prm.b_wk   = (const float*)d_in[12];
  prm.w_ws   = (const float*)d_in[13];
  prm.b_ws   = (const float*)d_in[14];
  prm.w_er   = (const float*)d_in[15];
  prm.b_er   = (const float*)d_in[16];
  prm.w_ad   = (const float*)d_in[17];
  prm.b_ad   = (const float*)d_in[18];
  prm.ln_rk_g= (const float*)d_in[19];
  prm.ln_rk_b= (const float*)d_in[20];
  prm.ln_wk_g= (const float*)d_in[21];
  prm.ln_wk_b= (const float*)d_in[22];
  prm.ln_m_g = (const float*)d_in[23];
  prm.ln_m_b = (const float*)d_in[24];
  prm.ln_o_g = (const float*)d_in[25];
  prm.ln_o_b = (const float*)d_in[26];
  prm.w_p    = (const float*)d_in[27];
  prm.b_p    = (const float*)d_in[28];

  float* out = (float*)d_out;
  prm.y   = out + OUT_Y;
  prm.mem = out + OUT_MEM;
  prm.ht  = out + OUT_HT;
  prm.ct  = out + OUT_CT;

  prm.bar = (unsigned*)d_ws;
  hipMemsetAsync(d_ws, 0, 64, stream);

  float* ws = (float*)((char*)d_ws + 256);
  size_t o = 0;
  prm.h     = ws + o; o += 2*BB*HH;
  prm.c     = ws + o; o += BB*HH;
  prm.hn    = ws + o; o += BB*HH;
  prm.ci    = ws + o; o += BB*CIN;
  prm.rkn   = ws + o; o += BB*RR*HSZ;
  prm.wkn   = ws + o; o += BB*HSZ;
  prm.ers   = ws + o; o += BB*HSZ;
  prm.ads   = ws + o; o += BB*HSZ;
  prm.wss   = ws + o; o += BB;
  prm.orow  = ws + o; o += BB*PO;

  int dev = 0;
  hipGetDevice(&dev);
  int ncu = 0;
  hipDeviceGetAttribute(&ncu, hipDeviceAttributeMultiprocessorCount, dev);
  if (ncu <= 0) ncu = 64;
  int nb = ncu < NBLK ? ncu : NBLK;
  int nbp = 1;
  while (nbp * 2 <= nb) nbp *= 2;

  dnc_all<<<dim3(nbp), dim3(256), 0, stream>>>(prm);
}

// Round 7
// 52224.329 us; speedup vs baseline: 2.6881x; 1.0651x over previous
//
#include <hip/hip_runtime.h>
#include <math.h>

#define BB 64
#define LL 256
#define EE 512
#define HH 1024
#define MM 2048
#define HSZ 64
#define RR 4
#define CIN 768
#define PO 1280
#define OO 1024
#define EPSF 1e-5f
#define NBLK 256
#define NT 512

// ---- d_out layout (float offsets) ----
#define OUT_Y    0
#define OUT_MEM  (BB * LL * OO)
#define OUT_HT   (OUT_MEM + BB * MM * HSZ)
#define OUT_CT   (OUT_HT + BB * HH)

// ---- persistent LDS region (floats, offsets into smem) ----
#define P_HN   10368
#define P_RKN  (P_HN + 1024)
#define P_WKN  (P_RKN + 256)
#define P_ERS  (P_WKN + 64)
#define P_ADS  (P_ERS + 64)
#define P_WSS  (P_ADS + 64)
#define SMEM_F 13056

struct Params {
  const float *x_emb, *ln_in_g, *ln_in_b, *w_ih, *w_hh, *b_ih, *b_hh;
  const float *ln_c_g, *ln_c_b, *w_rk, *b_rk, *w_wk, *b_wk, *w_ws, *b_ws;
  const float *w_er, *b_er, *w_ad, *b_ad, *ln_rk_g, *ln_rk_b, *ln_wk_g, *ln_wk_b;
  const float *ln_m_g, *ln_m_b, *ln_o_g, *ln_o_b, *w_p, *b_p;
  float *y, *mem, *ht, *ct;
  float *h, *c, *ci, *orow;   // orow is [2][BB][PO] double-buffered
  unsigned *bar;
};

__device__ __forceinline__ float sigm(float x){ return 1.f/(1.f+expf(-x)); }

// agent-scope coherent accessors for CROSS-BLOCK tensors only
__device__ __forceinline__ float dload(const float* p){
  return __hip_atomic_load(p, __ATOMIC_RELAXED, __HIP_MEMORY_SCOPE_AGENT);
}
__device__ __forceinline__ float2 dload2(const float* p){
  unsigned long long u = __hip_atomic_load((const unsigned long long*)p,
                                           __ATOMIC_RELAXED, __HIP_MEMORY_SCOPE_AGENT);
  float2 r; r.x = __uint_as_float((unsigned)(u & 0xffffffffull));
  r.y = __uint_as_float((unsigned)(u >> 32)); return r;
}
__device__ __forceinline__ void dstore(float* p, float v){
  __hip_atomic_store(p, v, __ATOMIC_RELAXED, __HIP_MEMORY_SCOPE_AGENT);
}

// monotone count-up grid barrier (no cache-maintenance fences; cross-block data
// goes through agent-scope accessors; vmcnt(0) drains them before arrival)
__device__ __forceinline__ void gbar(unsigned* bar, unsigned target) {
  __syncthreads();
  if (threadIdx.x == 0) {
    asm volatile("s_waitcnt vmcnt(0)" ::: "memory");
    __hip_atomic_fetch_add(bar, 1u, __ATOMIC_RELAXED, __HIP_MEMORY_SCOPE_AGENT);
    while (__hip_atomic_load(bar, __ATOMIC_RELAXED, __HIP_MEMORY_SCOPE_AGENT) < target) {
      __builtin_amdgcn_s_sleep(8);
    }
    asm volatile("" ::: "memory");
  }
  __syncthreads();
}

// block-wide (512-thread, 8-wave) reductions
__device__ __forceinline__ float bsum(float v, volatile float* red){
  __syncthreads();
  for (int o=32;o>0;o>>=1) v += __shfl_down(v,o,64);
  int w = threadIdx.x>>6;
  if ((threadIdx.x&63)==0) red[w]=v;
  __syncthreads();
  return red[0]+red[1]+red[2]+red[3]+red[4]+red[5]+red[6]+red[7];
}
__device__ __forceinline__ float bmax(float v, volatile float* red){
  __syncthreads();
  for (int o=32;o>0;o>>=1) v = fmaxf(v,__shfl_down(v,o,64));
  int w = threadIdx.x>>6;
  if ((threadIdx.x&63)==0) red[w]=v;
  __syncthreads();
  float a = fmaxf(fmaxf(red[0],red[1]),fmaxf(red[2],red[3]));
  float b = fmaxf(fmaxf(red[4],red[5]),fmaxf(red[6],red[7]));
  return fmaxf(a,b);
}

__device__ __forceinline__ float row_score(const float4* v, const float* wk,
                                           const float* g, const float* bt){
  float sum=0.f;
  #pragma unroll
  for (int i=0;i<16;++i) sum += v[i].x+v[i].y+v[i].z+v[i].w;
  float mu = sum*(1.f/64.f);
  float ssq=0.f;
  #pragma unroll
  for (int i=0;i<16;++i){ float dx=v[i].x-mu,dy=v[i].y-mu,dz=v[i].z-mu,dw=v[i].w-mu;
                          ssq+=dx*dx+dy*dy+dz*dz+dw*dw; }
  float rstd = rsqrtf(ssq*(1.f/64.f)+EPSF);
  float sc=0.f;
  #pragma unroll
  for (int i=0;i<16;++i){ int h=i*4;
    sc += ((v[i].x-mu)*rstd*g[h  ]+bt[h  ])*wk[h  ];
    sc += ((v[i].y-mu)*rstd*g[h+1]+bt[h+1])*wk[h+1];
    sc += ((v[i].z-mu)*rstd*g[h+2]+bt[h+2])*wk[h+2];
    sc += ((v[i].w-mu)*rstd*g[h+3]+bt[h+3])*wk[h+3];
  }
  return sc;
}

// heads for one b: hn LN + 449-row GEMV + per-head LN/activations -> persistent LDS
__device__ void heads_b(const Params& p, int b, int tid, const float* hnew,
                        float* smem, volatile float* red){
  float* raw  = smem;            // 449
  float* pHn  = smem + P_HN;
  float2 hv = dload2(&hnew[b*HH + tid*2]);
  float s = bsum(hv.x + hv.y, red);
  float mu = s * (1.f/HH);
  float d0 = hv.x-mu, d1 = hv.y-mu;
  float ssq = bsum(d0*d0 + d1*d1, red);
  float rstd = rsqrtf(ssq*(1.f/HH)+EPSF);
  pHn[tid*2]   = d0*rstd*p.ln_c_g[tid*2]   + p.ln_c_b[tid*2];
  pHn[tid*2+1] = d1*rstd*p.ln_c_g[tid*2+1] + p.ln_c_b[tid*2+1];
  __syncthreads();
  if (tid < 449) {
    int gr = tid;
    const float* wrow; float bias;
    if (gr < 256)      { wrow = p.w_rk + (size_t)gr*HH;        bias = p.b_rk[gr]; }
    else if (gr < 320) { wrow = p.w_wk + (size_t)(gr-256)*HH;  bias = p.b_wk[gr-256]; }
    else if (gr == 320){ wrow = p.w_ws;                        bias = p.b_ws[0]; }
    else if (gr < 385) { wrow = p.w_er + (size_t)(gr-321)*HH;  bias = p.b_er[gr-321]; }
    else               { wrow = p.w_ad + (size_t)(gr-385)*HH;  bias = p.b_ad[gr-385]; }
    float acc = bias;
    #pragma unroll 8
    for (int k=0;k<HH;k+=4){
      float4 w4 = *(const float4*)&wrow[k];
      acc += w4.x*pHn[k]+w4.y*pHn[k+1]+w4.z*pHn[k+2]+w4.w*pHn[k+3];
    }
    raw[tid] = acc;
  }
  __syncthreads();
  if (tid < 256) {               // 4 read-key LNs (wave-aligned: head = tid>>6)
    int l = tid & 63;
    float v = raw[tid];
    float sv=v; for(int o=32;o>0;o>>=1) sv += __shfl_xor(sv,o,64);
    float m2 = sv*(1.f/64.f);
    float d = v-m2; float sq=d*d;
    for(int o=32;o>0;o>>=1) sq += __shfl_xor(sq,o,64);
    float rs = rsqrtf(sq*(1.f/64.f)+EPSF);
    smem[P_RKN + tid] = d*rs*p.ln_rk_g[l] + p.ln_rk_b[l];
  } else if (tid < 320) {        // write-key LN (wave 4)
    int l = tid - 256;
    float v = raw[256+l];
    float sv=v; for(int o=32;o>0;o>>=1) sv += __shfl_xor(sv,o,64);
    float m2 = sv*(1.f/64.f);
    float d=v-m2; float sq=d*d;
    for(int o=32;o>0;o>>=1) sq += __shfl_xor(sq,o,64);
    float rs = rsqrtf(sq*(1.f/64.f)+EPSF);
    smem[P_WKN + l] = d*rs*p.ln_wk_g[l] + p.ln_wk_b[l];
  } else if (tid < 384) {
    int l = tid - 320; smem[P_ERS + l] = sigm(raw[321+l]);
  } else if (tid < 448) {
    int l = tid - 384; smem[P_ADS + l] = tanhf(raw[385+l]);
  } else if (tid == 448) {
    smem[P_WSS] = sigm(raw[320]);
  }
}

// memory pipeline for one b (block-local mem slice + persistent LDS inputs)
__device__ void mem_b(const Params& p, int b, int tid, int t, float* smem, volatile float* red){
  float* bcg = smem;            // 128: ln_m_g | ln_m_b
  float* sw  = smem + 128;      // 2048
  float* srd = smem + 2176;     // 8192
  float* pHn  = smem + P_HN;
  float* pRkn = smem + P_RKN;
  float* pWkn = smem + P_WKN;
  float* pErs = smem + P_ERS;
  float* pAds = smem + P_ADS;
  if (tid < 64) { bcg[tid] = p.ln_m_g[tid]; bcg[64+tid] = p.ln_m_b[tid]; }
  __syncthreads();
  float wstr = smem[P_WSS];
  float* mb = p.mem + (size_t)b*MM*HSZ;

  // pass A: write scores (4 rows/thread)
  for (int k=0;k<4;++k){
    int m = k*NT + tid;
    const float4* row = (const float4*)(mb + (size_t)m*HSZ);
    float4 rr[16];
    #pragma unroll
    for (int j=0;j<16;++j) rr[j] = row[j];
    sw[m] = row_score(rr, pWkn, bcg, bcg+64);
  }
  __syncthreads();
  float mx = -3.4e38f;
  #pragma unroll
  for (int k=0;k<4;++k) mx = fmaxf(mx, sw[k*NT+tid]);
  mx = bmax(mx, red);
  float se = 0.f;
  #pragma unroll
  for (int k=0;k<4;++k) se += expf(sw[k*NT+tid]-mx);
  se = bsum(se, red);
  float winv = wstr / se;
  #pragma unroll
  for (int k=0;k<4;++k){ int m=k*NT+tid; sw[m] = expf(sw[m]-mx)*winv; }

  // pass B: update rows + read scores
  for (int k=0;k<4;++k){
    int m = k*NT + tid;
    float* row = mb + (size_t)m*HSZ;
    float4 rr[16];
    #pragma unroll
    for (int j=0;j<16;++j) rr[j] = ((const float4*)row)[j];
    float ww = sw[m];
    #pragma unroll
    for (int i=0;i<16;++i){ int h=i*4;
      rr[i].x = rr[i].x*(1.f-ww*pErs[h  ]) + ww*pAds[h  ];
      rr[i].y = rr[i].y*(1.f-ww*pErs[h+1]) + ww*pAds[h+1];
      rr[i].z = rr[i].z*(1.f-ww*pErs[h+2]) + ww*pAds[h+2];
      rr[i].w = rr[i].w*(1.f-ww*pErs[h+3]) + ww*pAds[h+3];
    }
    #pragma unroll
    for (int j=0;j<16;++j) ((float4*)row)[j] = rr[j];
    float sum=0.f;
    #pragma unroll
    for (int i=0;i<16;++i) sum += rr[i].x+rr[i].y+rr[i].z+rr[i].w;
    float mu = sum*(1.f/64.f);
    float ssq=0.f;
    #pragma unroll
    for (int i=0;i<16;++i){ float dx=rr[i].x-mu,dy=rr[i].y-mu,dz=rr[i].z-mu,dw=rr[i].w-mu;
                            ssq+=dx*dx+dy*dy+dz*dz+dw*dw; }
    float rstd = rsqrtf(ssq*(1.f/64.f)+EPSF);
    float t0=0,t1=0,t2=0,t3=0;
    #pragma unroll
    for (int i=0;i<16;++i){ int h=i*4;
      float n0=(rr[i].x-mu)*rstd*bcg[h  ]+bcg[64+h  ];
      float n1=(rr[i].y-mu)*rstd*bcg[h+1]+bcg[64+h+1];
      float n2=(rr[i].z-mu)*rstd*bcg[h+2]+bcg[64+h+2];
      float n3=(rr[i].w-mu)*rstd*bcg[h+3]+bcg[64+h+3];
      t0 += n0*pRkn[h    ]+n1*pRkn[h+1    ]+n2*pRkn[h+2    ]+n3*pRkn[h+3    ];
      t1 += n0*pRkn[64+h ]+n1*pRkn[64+h+1 ]+n2*pRkn[64+h+2 ]+n3*pRkn[64+h+3 ];
      t2 += n0*pRkn[128+h]+n1*pRkn[128+h+1]+n2*pRkn[128+h+2]+n3*pRkn[128+h+3];
      t3 += n0*pRkn[192+h]+n1*pRkn[192+h+1]+n2*pRkn[192+h+2]+n3*pRkn[192+h+3];
    }
    srd[m] = t0; srd[2048+m] = t1; srd[4096+m] = t2; srd[6144+m] = t3;
  }
  __syncthreads();
  #pragma unroll
  for (int n=0;n<RR;++n){
    float mxn = -3.4e38f;
    #pragma unroll
    for (int k=0;k<4;++k) mxn = fmaxf(mxn, srd[n*2048+k*NT+tid]);
    mxn = bmax(mxn, red);
    float sen = 0.f;
    #pragma unroll
    for (int k=0;k<4;++k) sen += expf(srd[n*2048+k*NT+tid]-mxn);
    sen = bsum(sen, red);
    float rinv = 1.f/sen;
    #pragma unroll
    for (int k=0;k<4;++k){ int m=k*NT+tid; srd[n*2048+m] = expf(srd[n*2048+m]-mxn)*rinv; }
  }
  __syncthreads();
  // pass C: rv gather, 8 loads in flight, 8-way m-split
  int hs = tid & 63, wv = tid >> 6;
  float a0=0,a1=0,a2=0,a3=0;
  for (int m0=0; m0<MM; m0+=64){
    float v[8];
    #pragma unroll
    for (int j=0;j<8;++j) v[j] = mb[(size_t)(m0 + wv + 8*j)*HSZ + hs];
    #pragma unroll
    for (int j=0;j<8;++j){
      int m = m0 + wv + 8*j;
      a0 += srd[m]*v[j]; a1 += srd[2048+m]*v[j]; a2 += srd[4096+m]*v[j]; a3 += srd[6144+m]*v[j];
    }
  }
  __syncthreads();   // srd reads done; sw free for partials
  sw[wv*256 + 0*64 + hs] = a0;
  sw[wv*256 + 1*64 + hs] = a1;
  sw[wv*256 + 2*64 + hs] = a2;
  sw[wv*256 + 3*64 + hs] = a3;
  __syncthreads();
  float rvv = 0.f;
  if (tid < 256) {
    int n2 = tid>>6, h2 = tid&63;
    #pragma unroll
    for (int w2=0; w2<8; ++w2) rvv += sw[w2*256 + n2*64 + h2];
  }
  // tail: orow = LN(concat(hn, rv)); ci(t+1) = LN(concat(x_{t+1}, rv))
  float* row   = srd;          // 1280
  float* cirow = srd + 1280;   // 768
  if (tid < 256) row[HH+tid] = rvv;
  for (int i=tid;i<HH;i+=NT) row[i] = pHn[i];
  __syncthreads();
  float s=0.f; for (int i=tid;i<PO;i+=NT) s+=row[i];
  float mu = bsum(s,red)*(1.f/PO);
  float ss=0.f; for (int i=tid;i<PO;i+=NT){ float d=row[i]-mu; ss+=d*d; }
  float rstd = rsqrtf(bsum(ss,red)*(1.f/PO)+EPSF);
  float* ob = p.orow + (size_t)(t&1)*BB*PO;
  for (int i=tid;i<PO;i+=NT)
    dstore(&ob[b*PO+i], (row[i]-mu)*rstd*p.ln_o_g[i]+p.ln_o_b[i]);
  if (t+1 < LL) {
    for (int i=tid;i<CIN;i+=NT)
      cirow[i] = (i<EE)? p.x_emb[(size_t)(b*LL+t+1)*EE+i] : row[HH+(i-EE)];
    __syncthreads();
    float s2=0.f; for (int i=tid;i<CIN;i+=NT) s2+=cirow[i];
    float mu2 = bsum(s2,red)*(1.f/CIN);
    float ss2=0.f; for (int i=tid;i<CIN;i+=NT){ float d=cirow[i]-mu2; ss2+=d*d; }
    float rstd2 = rsqrtf(bsum(ss2,red)*(1.f/CIN)+EPSF);
    for (int i=tid;i<CIN;i+=NT)
      dstore(&p.ci[b*CIN+i], (cirow[i]-mu2)*rstd2*p.ln_in_g[i]+p.ln_in_b[i]);
  }
}

// logits tile (512 threads, K split across two 256-thread subs, reg prefetch + swizzle)
__device__ void logits_tile(const Params& p, int w, int tid, int tprev, float* smem){
  const float* ob = p.orow + (size_t)(tprev&1)*BB*PO;
  int cgl = w & 15, bg = w >> 4;
  int sub = tid >> 8, stid = tid & 255;
  int tb = stid >> 4, cq = stid & 15;
  int ar = tb, ac = cq << 2;
  int b0 = bg*16, col0 = cgl*64;
  float (*A_)[68]  = (float(*)[68])smem;            // [32][68]
  float (*Wt_)[68] = (float(*)[68])(smem+2176);     // [128][68]
  float (*Lc_)[68] = (float(*)[68])(smem+10880);    // [32][68]
  int c0 = cq*4;
  float acc0=0,acc1=0,acc2=0,acc3=0;
  float2 a01, a23; float4 wPre[4];
  const int NIT = 10;   // 20 k-tiles / 2 subs
  // preload iter 0
  {
    int k0 = (0*2 + sub)*64;
    const float* ap = &ob[(b0+ar)*PO + k0 + ac];
    a01 = dload2(ap); a23 = dload2(ap+2);
    #pragma unroll
    for (int i2=0;i2<4;++i2){
      int idx2 = i2*256 + stid; int ccl = idx2>>4; int kq = (idx2&15)<<2;
      wPre[i2] = *(const float4*)&p.w_p[(size_t)(col0+ccl)*PO + k0 + kq];
    }
  }
  for (int it=0; it<NIT; ++it){
    __syncthreads();
    A_[sub*16+ar][ac]=a01.x; A_[sub*16+ar][ac+1]=a01.y;
    A_[sub*16+ar][ac+2]=a23.x; A_[sub*16+ar][ac+3]=a23.y;
    #pragma unroll
    for (int i2=0;i2<4;++i2){
      int idx2 = i2*256 + stid; int ccl = idx2>>4; int kq = (idx2&15)<<2;
      int swz = ((idx2&15)&7)<<2;
      int col = ccl ^ swz;
      Wt_[sub*64+kq  ][col]=wPre[i2].x; Wt_[sub*64+kq+1][col]=wPre[i2].y;
      Wt_[sub*64+kq+2][col]=wPre[i2].z; Wt_[sub*64+kq+3][col]=wPre[i2].w;
    }
    int nx = (it+1 < NIT) ? it+1 : it;
    {
      int k0 = (nx*2 + sub)*64;
      const float* ap = &ob[(b0+ar)*PO + k0 + ac];
      a01 = dload2(ap); a23 = dload2(ap+2);
      #pragma unroll
      for (int i2=0;i2<4;++i2){
        int idx2 = i2*256 + stid; int ccl = idx2>>4; int kq = (idx2&15)<<2;
        wPre[i2] = *(const float4*)&p.w_p[(size_t)(col0+ccl)*PO + k0 + kq];
      }
    }
    __syncthreads();
    #pragma unroll
    for (int kk=0;kk<16;++kk){
      float4 a4 = *(const float4*)&A_[sub*16+tb][kk*4];
      int cs = c0 ^ ((kk&7)<<2);
      float4 w0=*(const float4*)&Wt_[sub*64+kk*4  ][cs];
      float4 w1=*(const float4*)&Wt_[sub*64+kk*4+1][cs];
      float4 w2=*(const float4*)&Wt_[sub*64+kk*4+2][cs];
      float4 w3=*(const float4*)&Wt_[sub*64+kk*4+3][cs];
      acc0+=a4.x*w0.x; acc1+=a4.x*w0.y; acc2+=a4.x*w0.z; acc3+=a4.x*w0.w;
      acc0+=a4.y*w1.x; acc1+=a4.y*w1.y; acc2+=a4.y*w1.z; acc3+=a4.y*w1.w;
      acc0+=a4.z*w2.x; acc1+=a4.z*w2.y; acc2+=a4.z*w2.z; acc3+=a4.z*w2.w;
      acc0+=a4.w*w3.x; acc1+=a4.w*w3.y; acc2+=a4.w*w3.z; acc3+=a4.w*w3.w;
    }
  }
  Lc_[sub*16+tb][c0]=acc0; Lc_[sub*16+tb][c0+1]=acc1;
  Lc_[sub*16+tb][c0+2]=acc2; Lc_[sub*16+tb][c0+3]=acc3;
  __syncthreads();
  if (tid < 256) {
    int tb2 = tid>>4, jl = tid&15;
    int cc0 = jl*4;
    int col = col0 + cc0;
    float4 o;
    o.x = Lc_[tb2][cc0]  +Lc_[16+tb2][cc0]   + p.b_p[col];
    o.y = Lc_[tb2][cc0+1]+Lc_[16+tb2][cc0+1] + p.b_p[col+1];
    o.z = Lc_[tb2][cc0+2]+Lc_[16+tb2][cc0+2] + p.b_p[col+2];
    o.w = Lc_[tb2][cc0+3]+Lc_[16+tb2][cc0+3] + p.b_p[col+3];
    *(float4*)&p.y[(size_t)((b0+tb2)*LL + tprev)*OO + col] = o;
  }
  __syncthreads();
}

__global__ __launch_bounds__(NT, 2) void dnc_all(Params p) {
  __shared__ __align__(16) float smem[SMEM_F];
  __shared__ float red[8];
  const int blk = blockIdx.x, tid = threadIdx.x;
  const int NB = gridDim.x;
  unsigned bnum = 0;

  // ---------------- P0: init ----------------
  {
    for (int b = blk; b < BB; b += NB) {
      float4 z4 = make_float4(0.f,0.f,0.f,0.f);
      float4* m4 = (float4*)(p.mem + (size_t)b*MM*HSZ);
      for (int i = tid; i < (MM*HSZ)/4; i += NT) m4[i] = z4;
    }
    int gidx = blk*NT + tid;
    for (int i = gidx; i < BB*HH; i += NB*NT) dstore(&p.h[i], 0.f);
    for (int b = blk; b < BB; b += NB) {
      __syncthreads();
      for (int i = tid; i < CIN; i += NT)
        smem[i] = (i < EE) ? p.x_emb[(size_t)(b*LL)*EE + i] : 0.f;
      __syncthreads();
      float s = 0.f;
      for (int i = tid; i < CIN; i += NT) s += smem[i];
      float mu = bsum(s, red) * (1.f/CIN);
      float ss = 0.f;
      for (int i = tid; i < CIN; i += NT) { float d = smem[i]-mu; ss += d*d; }
      float rstd = rsqrtf(bsum(ss, red)*(1.f/CIN) + EPSF);
      for (int i = tid; i < CIN; i += NT)
        dstore(&p.ci[b*CIN+i], (smem[i]-mu)*rstd*p.ln_in_g[i] + p.ln_in_b[i]);
    }
  }
  gbar(p.bar, (++bnum)*NB);

  for (int t = 0; t < LL; ++t) {
    const float* hprev = p.h + (t & 1) * (BB*HH);
    float* hnew = p.h + ((t+1) & 1) * (BB*HH);

    // -------- P1: gates GEMM + LSTM (256 tiles; K split across 2 subs; reg prefetch) --------
    for (int w = blk; w < 256; w += NB) {
      int cgp = w & 63, bg = w >> 6;
      int sub = tid >> 8, stid = tid & 255;
      int tb = stid >> 4, cq = stid & 15;
      int ar = tb, ac = cq << 2;
      int b0 = bg*16, j0 = cgp*16;
      float (*A_)[68]  = (float(*)[68])smem;
      float (*Wt_)[68] = (float(*)[68])(smem+2176);
      float (*Gv_)[68] = (float(*)[68])(smem+10880);
      int c0 = cq*4;
      float acc0=0,acc1=0,acc2=0,acc3=0;
      float2 a01, a23; float4 wPre[4];
      const int NIT = 14;  // 6 (ci, K=768) + 8 (h, K=1024) per sub
      // preload iter 0
      {
        const float* As = p.ci; const float* Ws = p.w_ih; int K = CIN;
        int k0 = sub*64;
        const float* ap = &As[(b0+ar)*K + k0 + ac];
        a01 = dload2(ap); a23 = dload2(ap+2);
        #pragma unroll
        for (int i2=0;i2<4;++i2){
          int idx2 = i2*256 + stid; int ccl = idx2>>4; int kq = (idx2&15)<<2;
          int gate = ccl>>4, jl = ccl&15;
          wPre[i2] = *(const float4*)&Ws[(size_t)(gate*HH + j0 + jl)*K + k0 + kq];
        }
      }
      for (int it=0; it<NIT; ++it){
        __syncthreads();
        A_[sub*16+ar][ac]=a01.x; A_[sub*16+ar][ac+1]=a01.y;
        A_[sub*16+ar][ac+2]=a23.x; A_[sub*16+ar][ac+3]=a23.y;
        #pragma unroll
        for (int i2=0;i2<4;++i2){
          int idx2 = i2*256 + stid; int ccl = idx2>>4; int kq = (idx2&15)<<2;
          int swz = ((idx2&15)&7)<<2;
          int col = ccl ^ swz;
          Wt_[sub*64+kq  ][col]=wPre[i2].x; Wt_[sub*64+kq+1][col]=wPre[i2].y;
          Wt_[sub*64+kq+2][col]=wPre[i2].z; Wt_[sub*64+kq+3][col]=wPre[i2].w;
        }
        int nx = (it+1 < NIT) ? it+1 : it;
        {
          const float* As; const float* Ws; int K, k0;
          if (nx < 6){ As = p.ci;  Ws = p.w_ih; K = CIN; k0 = (nx*2 + sub)*64; }
          else       { As = hprev; Ws = p.w_hh; K = HH;  k0 = ((nx-6)*2 + sub)*64; }
          const float* ap = &As[(b0+ar)*K + k0 + ac];
          a01 = dload2(ap); a23 = dload2(ap+2);
          #pragma unroll
          for (int i2=0;i2<4;++i2){
            int idx2 = i2*256 + stid; int ccl = idx2>>4; int kq = (idx2&15)<<2;
            int gate = ccl>>4, jl = ccl&15;
            wPre[i2] = *(const float4*)&Ws[(size_t)(gate*HH + j0 + jl)*K + k0 + kq];
          }
        }
        __syncthreads();
        #pragma unroll
        for (int kk=0;kk<16;++kk){
          float4 a4 = *(const float4*)&A_[sub*16+tb][kk*4];
          int cs = c0 ^ ((kk&7)<<2);
          float4 w0=*(const float4*)&Wt_[sub*64+kk*4  ][cs];
          float4 w1=*(const float4*)&Wt_[sub*64+kk*4+1][cs];
          float4 w2=*(const float4*)&Wt_[sub*64+kk*4+2][cs];
          float4 w3=*(const float4*)&Wt_[sub*64+kk*4+3][cs];
          acc0+=a4.x*w0.x; acc1+=a4.x*w0.y; acc2+=a4.x*w0.z; acc3+=a4.x*w0.w;
          acc0+=a4.y*w1.x; acc1+=a4.y*w1.y; acc2+=a4.y*w1.z; acc3+=a4.y*w1.w;
          acc0+=a4.z*w2.x; acc1+=a4.z*w2.y; acc2+=a4.z*w2.z; acc3+=a4.z*w2.w;
          acc0+=a4.w*w3.x; acc1+=a4.w*w3.y; acc2+=a4.w*w3.z; acc3+=a4.w*w3.w;
        }
      }
      Gv_[sub*16+tb][c0]=acc0; Gv_[sub*16+tb][c0+1]=acc1;
      Gv_[sub*16+tb][c0+2]=acc2; Gv_[sub*16+tb][c0+3]=acc3;
      __syncthreads();
      if (tid < 256) {
        int tb2 = tid>>4, jl = tid&15;
        int r0 = 0*HH + j0 + jl, r1 = 1*HH + j0 + jl, r2 = 2*HH + j0 + jl, r3 = 3*HH + j0 + jl;
        float gi = Gv_[tb2][jl]    + Gv_[16+tb2][jl]    + p.b_ih[r0]+p.b_hh[r0];
        float gf = Gv_[tb2][16+jl] + Gv_[16+tb2][16+jl] + p.b_ih[r1]+p.b_hh[r1];
        float gg = Gv_[tb2][32+jl] + Gv_[16+tb2][32+jl] + p.b_ih[r2]+p.b_hh[r2];
        float go = Gv_[tb2][48+jl] + Gv_[16+tb2][48+jl] + p.b_ih[r3]+p.b_hh[r3];
        int idx3 = (b0+tb2)*HH + j0 + jl;
        float cold = (t==0) ? 0.f : p.c[idx3];   // c tile-local (stable tile->block map)
        float cn = sigm(gf)*cold + sigm(gi)*tanhf(gg);
        float hv = sigm(go)*tanhf(cn);
        p.c[idx3] = cn;
        dstore(&hnew[idx3], hv);
        if (t == LL-1) { p.ht[idx3] = hv; p.ct[idx3] = cn; }
      }
      __syncthreads();
    }
    gbar(p.bar, (++bnum)*NB);

    // -------- Pb: heads+mem (blocks owning b) || logits(t-1) (next 64 blocks) --------
    for (int b = blk; b < BB; b += NB) {
      heads_b(p, b, tid, hnew, smem, red);
      __syncthreads();
      mem_b(p, b, tid, t, smem, red);
      __syncthreads();
    }
    if (t > 0) {
      for (int w = blk; w < 128; w += NB)
        if (w >= 64) logits_tile(p, w-64, tid, t-1, smem);
    }
    gbar(p.bar, (++bnum)*NB);
  }

  // ---------------- finale: logits(255) ----------------
  for (int w = blk; w < 128; w += NB)
    if (w >= 64) logits_tile(p, w-64, tid, LL-1, smem);
}

extern "C" void kernel_launch(void* const* d_in, const int* in_sizes, int n_in,
                              void* d_out, int out_size, void* d_ws, size_t ws_size,
                              hipStream_t stream) {
  Params prm;
  prm.x_emb  = (const float*)d_in[0];
  prm.ln_in_g= (const float*)d_in[1];
  prm.ln_in_b= (const float*)d_in[2];
  prm.w_ih   = (const float*)d_in[3];
  prm.w_hh   = (const float*)d_in[4];
  prm.b_ih   = (const float*)d_in[5];
  prm.b_hh   = (const float*)d_in[6];
  prm.ln_c_g = (const float*)d_in[7];
  prm.ln_c_b = (const float*)d_in[8];
  prm.w_rk   = (const float*)d_in[9];
  prm.b_rk   = (const float*)d_in[10];
  prm.w_wk   = (const float*)d_in[11];
  prm.b_wk   = (const float*)d_in[12];
  prm.w_ws   = (const float*)d_in[13];
  prm.b_ws   = (const float*)d_in[14];
  prm.w_er   = (const float*)d_in[15];
  prm.b_er   = (const float*)d_in[16];
  prm.w_ad   = (const float*)d_in[17];
  prm.b_ad   = (const float*)d_in[18];
  prm.ln_rk_g= (const float*)d_in[19];
  prm.ln_rk_b= (const float*)d_in[20];
  prm.ln_wk_g= (const float*)d_in[21];
  prm.ln_wk_b= (const float*)d_in[22];
  prm.ln_m_g = (const float*)d_in[23];
  prm.ln_m_b = (const float*)d_in[24];
  prm.ln_o_g = (const float*)d_in[25];
  prm.ln_o_b = (const float*)d_in[26];
  prm.w_p    = (const float*)d_in[27];
  prm.b_p    = (const float*)d_in[28];

  float* out = (float*)d_out;
  prm.y   = out + OUT_Y;
  prm.mem = out + OUT_MEM;
  prm.ht  = out + OUT_HT;
  prm.ct  = out + OUT_CT;

  prm.bar = (unsigned*)d_ws;
  hipMemsetAsync(d_ws, 0, 64, stream);

  float* ws = (float*)((char*)d_ws + 256);
  size_t o = 0;
  prm.h     = ws + o; o += 2*BB*HH;
  prm.c     = ws + o; o += BB*HH;
  prm.ci    = ws + o; o += BB*CIN;
  prm.orow  = ws + o; o += 2*BB*PO;

  int dev = 0;
  hipGetDevice(&dev);
  int ncu = 0;
  hipDeviceGetAttribute(&ncu, hipDeviceAttributeMultiprocessorCount, dev);
  if (ncu <= 0) ncu = 64;
  int nb = ncu < NBLK ? ncu : NBLK;
  int nbp = 1;
  while (nbp * 2 <= nb) nbp *= 2;

  dnc_all<<<dim3(nbp), dim3(NT), 0, stream>>>(prm);
}

// Round 8
// 51529.095 us; speedup vs baseline: 2.7244x; 1.0135x over previous
//
#include <hip/hip_runtime.h>
#include <math.h>

#define BB 64
#define LL 256
#define EE 512
#define HH 1024
#define MM 2048
#define HSZ 64
#define RR 4
#define CIN 768
#define PO 1280
#define OO 1024
#define EPSF 1e-5f
#define NBLK 256
#define NT 512

// ---- d_out layout (float offsets) ----
#define OUT_Y    0
#define OUT_MEM  (BB * LL * OO)
#define OUT_HT   (OUT_MEM + BB * MM * HSZ)
#define OUT_CT   (OUT_HT + BB * HH)

// ---- persistent LDS region (floats, offsets into smem) ----
#define P_HN   10368
#define P_RKN  (P_HN + 1024)
#define P_WKN  (P_RKN + 256)
#define P_ERS  (P_WKN + 64)
#define P_ADS  (P_ERS + 64)
#define P_WSS  (P_ADS + 64)
#define SMEM_F 13056

struct Params {
  const float *x_emb, *ln_in_g, *ln_in_b, *w_ih, *w_hh, *b_ih, *b_hh;
  const float *ln_c_g, *ln_c_b, *w_rk, *b_rk, *w_wk, *b_wk, *w_ws, *b_ws;
  const float *w_er, *b_er, *w_ad, *b_ad, *ln_rk_g, *ln_rk_b, *ln_wk_g, *ln_wk_b;
  const float *ln_m_g, *ln_m_b, *ln_o_g, *ln_o_b, *w_p, *b_p;
  float *y, *mem, *ht, *ct;
  float *h, *c, *ci, *orow;   // orow is [2][BB][PO] double-buffered
  unsigned *bar;
};

__device__ __forceinline__ float sigm(float x){ return 1.f/(1.f+expf(-x)); }

// agent-scope coherent accessors for CROSS-BLOCK tensors only
__device__ __forceinline__ float dload(const float* p){
  return __hip_atomic_load(p, __ATOMIC_RELAXED, __HIP_MEMORY_SCOPE_AGENT);
}
__device__ __forceinline__ float2 dload2(const float* p){
  unsigned long long u = __hip_atomic_load((const unsigned long long*)p,
                                           __ATOMIC_RELAXED, __HIP_MEMORY_SCOPE_AGENT);
  float2 r; r.x = __uint_as_float((unsigned)(u & 0xffffffffull));
  r.y = __uint_as_float((unsigned)(u >> 32)); return r;
}
__device__ __forceinline__ void dstore(float* p, float v){
  __hip_atomic_store(p, v, __ATOMIC_RELAXED, __HIP_MEMORY_SCOPE_AGENT);
}

// LDS-only barrier: orders LDS traffic (lgkmcnt) WITHOUT draining vmcnt, so
// global prefetch loads stay in flight across the barrier (T3/T4 mechanism).
// __syncthreads() would force s_waitcnt vmcnt(0) and kill the pipeline.
__device__ __forceinline__ void lds_barrier() {
  asm volatile("s_waitcnt lgkmcnt(0)" ::: "memory");
  __builtin_amdgcn_sched_barrier(0);
  __builtin_amdgcn_s_barrier();
  __builtin_amdgcn_sched_barrier(0);
}

// monotone count-up grid barrier (no cache-maintenance fences; cross-block data
// goes through agent-scope accessors; vmcnt(0) drains them before arrival)
__device__ __forceinline__ void gbar(unsigned* bar, unsigned target) {
  __syncthreads();
  if (threadIdx.x == 0) {
    asm volatile("s_waitcnt vmcnt(0)" ::: "memory");
    __hip_atomic_fetch_add(bar, 1u, __ATOMIC_RELAXED, __HIP_MEMORY_SCOPE_AGENT);
    while (__hip_atomic_load(bar, __ATOMIC_RELAXED, __HIP_MEMORY_SCOPE_AGENT) < target) {
      __builtin_amdgcn_s_sleep(8);
    }
    asm volatile("" ::: "memory");
  }
  __syncthreads();
}

// block-wide (512-thread, 8-wave) reductions
__device__ __forceinline__ float bsum(float v, volatile float* red){
  __syncthreads();
  for (int o=32;o>0;o>>=1) v += __shfl_down(v,o,64);
  int w = threadIdx.x>>6;
  if ((threadIdx.x&63)==0) red[w]=v;
  __syncthreads();
  return red[0]+red[1]+red[2]+red[3]+red[4]+red[5]+red[6]+red[7];
}
__device__ __forceinline__ float bmax(float v, volatile float* red){
  __syncthreads();
  for (int o=32;o>0;o>>=1) v = fmaxf(v,__shfl_down(v,o,64));
  int w = threadIdx.x>>6;
  if ((threadIdx.x&63)==0) red[w]=v;
  __syncthreads();
  float a = fmaxf(fmaxf(red[0],red[1]),fmaxf(red[2],red[3]));
  float b = fmaxf(fmaxf(red[4],red[5]),fmaxf(red[6],red[7]));
  return fmaxf(a,b);
}

__device__ __forceinline__ float row_score(const float4* v, const float* wk,
                                           const float* g, const float* bt){
  float sum=0.f;
  #pragma unroll
  for (int i=0;i<16;++i) sum += v[i].x+v[i].y+v[i].z+v[i].w;
  float mu = sum*(1.f/64.f);
  float ssq=0.f;
  #pragma unroll
  for (int i=0;i<16;++i){ float dx=v[i].x-mu,dy=v[i].y-mu,dz=v[i].z-mu,dw=v[i].w-mu;
                          ssq+=dx*dx+dy*dy+dz*dz+dw*dw; }
  float rstd = rsqrtf(ssq*(1.f/64.f)+EPSF);
  float sc=0.f;
  #pragma unroll
  for (int i=0;i<16;++i){ int h=i*4;
    sc += ((v[i].x-mu)*rstd*g[h  ]+bt[h  ])*wk[h  ];
    sc += ((v[i].y-mu)*rstd*g[h+1]+bt[h+1])*wk[h+1];
    sc += ((v[i].z-mu)*rstd*g[h+2]+bt[h+2])*wk[h+2];
    sc += ((v[i].w-mu)*rstd*g[h+3]+bt[h+3])*wk[h+3];
  }
  return sc;
}

// heads for one b: hn LN + 449-row GEMV + per-head LN/activations -> persistent LDS
__device__ void heads_b(const Params& p, int b, int tid, const float* hnew,
                        float* smem, volatile float* red){
  float* raw  = smem;            // 449
  float* pHn  = smem + P_HN;
  float2 hv = dload2(&hnew[b*HH + tid*2]);
  float s = bsum(hv.x + hv.y, red);
  float mu = s * (1.f/HH);
  float d0 = hv.x-mu, d1 = hv.y-mu;
  float ssq = bsum(d0*d0 + d1*d1, red);
  float rstd = rsqrtf(ssq*(1.f/HH)+EPSF);
  pHn[tid*2]   = d0*rstd*p.ln_c_g[tid*2]   + p.ln_c_b[tid*2];
  pHn[tid*2+1] = d1*rstd*p.ln_c_g[tid*2+1] + p.ln_c_b[tid*2+1];
  __syncthreads();
  if (tid < 449) {
    int gr = tid;
    const float* wrow; float bias;
    if (gr < 256)      { wrow = p.w_rk + (size_t)gr*HH;        bias = p.b_rk[gr]; }
    else if (gr < 320) { wrow = p.w_wk + (size_t)(gr-256)*HH;  bias = p.b_wk[gr-256]; }
    else if (gr == 320){ wrow = p.w_ws;                        bias = p.b_ws[0]; }
    else if (gr < 385) { wrow = p.w_er + (size_t)(gr-321)*HH;  bias = p.b_er[gr-321]; }
    else               { wrow = p.w_ad + (size_t)(gr-385)*HH;  bias = p.b_ad[gr-385]; }
    float acc = bias;
    #pragma unroll 8
    for (int k=0;k<HH;k+=4){
      float4 w4 = *(const float4*)&wrow[k];
      acc += w4.x*pHn[k]+w4.y*pHn[k+1]+w4.z*pHn[k+2]+w4.w*pHn[k+3];
    }
    raw[tid] = acc;
  }
  __syncthreads();
  if (tid < 256) {               // 4 read-key LNs (wave-aligned: head = tid>>6)
    int l = tid & 63;
    float v = raw[tid];
    float sv=v; for(int o=32;o>0;o>>=1) sv += __shfl_xor(sv,o,64);
    float m2 = sv*(1.f/64.f);
    float d = v-m2; float sq=d*d;
    for(int o=32;o>0;o>>=1) sq += __shfl_xor(sq,o,64);
    float rs = rsqrtf(sq*(1.f/64.f)+EPSF);
    smem[P_RKN + tid] = d*rs*p.ln_rk_g[l] + p.ln_rk_b[l];
  } else if (tid < 320) {        // write-key LN (wave 4)
    int l = tid - 256;
    float v = raw[256+l];
    float sv=v; for(int o=32;o>0;o>>=1) sv += __shfl_xor(sv,o,64);
    float m2 = sv*(1.f/64.f);
    float d=v-m2; float sq=d*d;
    for(int o=32;o>0;o>>=1) sq += __shfl_xor(sq,o,64);
    float rs = rsqrtf(sq*(1.f/64.f)+EPSF);
    smem[P_WKN + l] = d*rs*p.ln_wk_g[l] + p.ln_wk_b[l];
  } else if (tid < 384) {
    int l = tid - 320; smem[P_ERS + l] = sigm(raw[321+l]);
  } else if (tid < 448) {
    int l = tid - 384; smem[P_ADS + l] = tanhf(raw[385+l]);
  } else if (tid == 448) {
    smem[P_WSS] = sigm(raw[320]);
  }
}

// memory pipeline for one b (block-local mem slice + persistent LDS inputs)
__device__ void mem_b(const Params& p, int b, int tid, int t, float* smem, volatile float* red){
  float* bcg = smem;            // 128: ln_m_g | ln_m_b
  float* sw  = smem + 128;      // 2048
  float* srd = smem + 2176;     // 8192
  float* pHn  = smem + P_HN;
  float* pRkn = smem + P_RKN;
  float* pWkn = smem + P_WKN;
  float* pErs = smem + P_ERS;
  float* pAds = smem + P_ADS;
  if (tid < 64) { bcg[tid] = p.ln_m_g[tid]; bcg[64+tid] = p.ln_m_b[tid]; }
  __syncthreads();
  float wstr = smem[P_WSS];
  float* mb = p.mem + (size_t)b*MM*HSZ;

  // pass A: write scores (4 rows/thread)
  for (int k=0;k<4;++k){
    int m = k*NT + tid;
    const float4* row = (const float4*)(mb + (size_t)m*HSZ);
    float4 rr[16];
    #pragma unroll
    for (int j=0;j<16;++j) rr[j] = row[j];
    sw[m] = row_score(rr, pWkn, bcg, bcg+64);
  }
  __syncthreads();
  float mx = -3.4e38f;
  #pragma unroll
  for (int k=0;k<4;++k) mx = fmaxf(mx, sw[k*NT+tid]);
  mx = bmax(mx, red);
  float se = 0.f;
  #pragma unroll
  for (int k=0;k<4;++k) se += expf(sw[k*NT+tid]-mx);
  se = bsum(se, red);
  float winv = wstr / se;
  #pragma unroll
  for (int k=0;k<4;++k){ int m=k*NT+tid; sw[m] = expf(sw[m]-mx)*winv; }

  // pass B: update rows + read scores
  for (int k=0;k<4;++k){
    int m = k*NT + tid;
    float* row = mb + (size_t)m*HSZ;
    float4 rr[16];
    #pragma unroll
    for (int j=0;j<16;++j) rr[j] = ((const float4*)row)[j];
    float ww = sw[m];
    #pragma unroll
    for (int i=0;i<16;++i){ int h=i*4;
      rr[i].x = rr[i].x*(1.f-ww*pErs[h  ]) + ww*pAds[h  ];
      rr[i].y = rr[i].y*(1.f-ww*pErs[h+1]) + ww*pAds[h+1];
      rr[i].z = rr[i].z*(1.f-ww*pErs[h+2]) + ww*pAds[h+2];
      rr[i].w = rr[i].w*(1.f-ww*pErs[h+3]) + ww*pAds[h+3];
    }
    #pragma unroll
    for (int j=0;j<16;++j) ((float4*)row)[j] = rr[j];
    float sum=0.f;
    #pragma unroll
    for (int i=0;i<16;++i) sum += rr[i].x+rr[i].y+rr[i].z+rr[i].w;
    float mu = sum*(1.f/64.f);
    float ssq=0.f;
    #pragma unroll
    for (int i=0;i<16;++i){ float dx=rr[i].x-mu,dy=rr[i].y-mu,dz=rr[i].z-mu,dw=rr[i].w-mu;
                            ssq+=dx*dx+dy*dy+dz*dz+dw*dw; }
    float rstd = rsqrtf(ssq*(1.f/64.f)+EPSF);
    float t0=0,t1=0,t2=0,t3=0;
    #pragma unroll
    for (int i=0;i<16;++i){ int h=i*4;
      float n0=(rr[i].x-mu)*rstd*bcg[h  ]+bcg[64+h  ];
      float n1=(rr[i].y-mu)*rstd*bcg[h+1]+bcg[64+h+1];
      float n2=(rr[i].z-mu)*rstd*bcg[h+2]+bcg[64+h+2];
      float n3=(rr[i].w-mu)*rstd*bcg[h+3]+bcg[64+h+3];
      t0 += n0*pRkn[h    ]+n1*pRkn[h+1    ]+n2*pRkn[h+2    ]+n3*pRkn[h+3    ];
      t1 += n0*pRkn[64+h ]+n1*pRkn[64+h+1 ]+n2*pRkn[64+h+2 ]+n3*pRkn[64+h+3 ];
      t2 += n0*pRkn[128+h]+n1*pRkn[128+h+1]+n2*pRkn[128+h+2]+n3*pRkn[128+h+3];
      t3 += n0*pRkn[192+h]+n1*pRkn[192+h+1]+n2*pRkn[192+h+2]+n3*pRkn[192+h+3];
    }
    srd[m] = t0; srd[2048+m] = t1; srd[4096+m] = t2; srd[6144+m] = t3;
  }
  __syncthreads();
  #pragma unroll
  for (int n=0;n<RR;++n){
    float mxn = -3.4e38f;
    #pragma unroll
    for (int k=0;k<4;++k) mxn = fmaxf(mxn, srd[n*2048+k*NT+tid]);
    mxn = bmax(mxn, red);
    float sen = 0.f;
    #pragma unroll
    for (int k=0;k<4;++k) sen += expf(srd[n*2048+k*NT+tid]-mxn);
    sen = bsum(sen, red);
    float rinv = 1.f/sen;
    #pragma unroll
    for (int k=0;k<4;++k){ int m=k*NT+tid; srd[n*2048+m] = expf(srd[n*2048+m]-mxn)*rinv; }
  }
  __syncthreads();
  // pass C: rv gather, 8 loads in flight, 8-way m-split
  int hs = tid & 63, wv = tid >> 6;
  float a0=0,a1=0,a2=0,a3=0;
  for (int m0=0; m0<MM; m0+=64){
    float v[8];
    #pragma unroll
    for (int j=0;j<8;++j) v[j] = mb[(size_t)(m0 + wv + 8*j)*HSZ + hs];
    #pragma unroll
    for (int j=0;j<8;++j){
      int m = m0 + wv + 8*j;
      a0 += srd[m]*v[j]; a1 += srd[2048+m]*v[j]; a2 += srd[4096+m]*v[j]; a3 += srd[6144+m]*v[j];
    }
  }
  __syncthreads();   // srd reads done; sw free for partials
  sw[wv*256 + 0*64 + hs] = a0;
  sw[wv*256 + 1*64 + hs] = a1;
  sw[wv*256 + 2*64 + hs] = a2;
  sw[wv*256 + 3*64 + hs] = a3;
  __syncthreads();
  float rvv = 0.f;
  if (tid < 256) {
    int n2 = tid>>6, h2 = tid&63;
    #pragma unroll
    for (int w2=0; w2<8; ++w2) rvv += sw[w2*256 + n2*64 + h2];
  }
  // tail: orow = LN(concat(hn, rv)); ci(t+1) = LN(concat(x_{t+1}, rv))
  float* row   = srd;          // 1280
  float* cirow = srd + 1280;   // 768
  if (tid < 256) row[HH+tid] = rvv;
  for (int i=tid;i<HH;i+=NT) row[i] = pHn[i];
  __syncthreads();
  float s=0.f; for (int i=tid;i<PO;i+=NT) s+=row[i];
  float mu = bsum(s,red)*(1.f/PO);
  float ss=0.f; for (int i=tid;i<PO;i+=NT){ float d=row[i]-mu; ss+=d*d; }
  float rstd = rsqrtf(bsum(ss,red)*(1.f/PO)+EPSF);
  float* ob = p.orow + (size_t)(t&1)*BB*PO;
  for (int i=tid;i<PO;i+=NT)
    dstore(&ob[b*PO+i], (row[i]-mu)*rstd*p.ln_o_g[i]+p.ln_o_b[i]);
  if (t+1 < LL) {
    for (int i=tid;i<CIN;i+=NT)
      cirow[i] = (i<EE)? p.x_emb[(size_t)(b*LL+t+1)*EE+i] : row[HH+(i-EE)];
    __syncthreads();
    float s2=0.f; for (int i=tid;i<CIN;i+=NT) s2+=cirow[i];
    float mu2 = bsum(s2,red)*(1.f/CIN);
    float ss2=0.f; for (int i=tid;i<CIN;i+=NT){ float d=cirow[i]-mu2; ss2+=d*d; }
    float rstd2 = rsqrtf(bsum(ss2,red)*(1.f/CIN)+EPSF);
    for (int i=tid;i<CIN;i+=NT)
      dstore(&p.ci[b*CIN+i], (cirow[i]-mu2)*rstd2*p.ln_in_g[i]+p.ln_in_b[i]);
  }
}

// logits tile (512 threads, K split across two 256-thread subs, reg prefetch + swizzle)
// Inner loop uses lds_barrier() so the w_p/orow prefetch stays in flight across barriers.
__device__ void logits_tile(const Params& p, int w, int tid, int tprev, float* smem){
  const float* ob = p.orow + (size_t)(tprev&1)*BB*PO;
  int cgl = w & 15, bg = w >> 4;
  int sub = tid >> 8, stid = tid & 255;
  int tb = stid >> 4, cq = stid & 15;
  int ar = tb, ac = cq << 2;
  int b0 = bg*16, col0 = cgl*64;
  float (*A_)[68]  = (float(*)[68])smem;            // [32][68]
  float (*Wt_)[68] = (float(*)[68])(smem+2176);     // [128][68]
  float (*Lc_)[68] = (float(*)[68])(smem+10880);    // [32][68]
  int c0 = cq*4;
  float acc0=0,acc1=0,acc2=0,acc3=0;
  float2 a01, a23; float4 wPre[4];
  const int NIT = 10;   // 20 k-tiles / 2 subs
  // preload iter 0
  {
    int k0 = (0*2 + sub)*64;
    const float* ap = &ob[(b0+ar)*PO + k0 + ac];
    a01 = dload2(ap); a23 = dload2(ap+2);
    #pragma unroll
    for (int i2=0;i2<4;++i2){
      int idx2 = i2*256 + stid; int ccl = idx2>>4; int kq = (idx2&15)<<2;
      wPre[i2] = *(const float4*)&p.w_p[(size_t)(col0+ccl)*PO + k0 + kq];
    }
  }
  for (int it=0; it<NIT; ++it){
    // write LDS from regs (compiler inserts counted vmcnt waits for these regs)
    A_[sub*16+ar][ac]=a01.x; A_[sub*16+ar][ac+1]=a01.y;
    A_[sub*16+ar][ac+2]=a23.x; A_[sub*16+ar][ac+3]=a23.y;
    #pragma unroll
    for (int i2=0;i2<4;++i2){
      int idx2 = i2*256 + stid; int ccl = idx2>>4; int kq = (idx2&15)<<2;
      int swz = ((idx2&15)&7)<<2;
      int col = ccl ^ swz;
      Wt_[sub*64+kq  ][col]=wPre[i2].x; Wt_[sub*64+kq+1][col]=wPre[i2].y;
      Wt_[sub*64+kq+2][col]=wPre[i2].z; Wt_[sub*64+kq+3][col]=wPre[i2].w;
    }
    // issue prefetch for it+1 (stays in flight across both barriers + compute)
    int nx = (it+1 < NIT) ? it+1 : it;
    {
      int k0 = (nx*2 + sub)*64;
      const float* ap = &ob[(b0+ar)*PO + k0 + ac];
      a01 = dload2(ap); a23 = dload2(ap+2);
      #pragma unroll
      for (int i2=0;i2<4;++i2){
        int idx2 = i2*256 + stid; int ccl = idx2>>4; int kq = (idx2&15)<<2;
        wPre[i2] = *(const float4*)&p.w_p[(size_t)(col0+ccl)*PO + k0 + kq];
      }
    }
    lds_barrier();   // LDS writes visible; vmcnt NOT drained
    #pragma unroll
    for (int kk=0;kk<16;++kk){
      float4 a4 = *(const float4*)&A_[sub*16+tb][kk*4];
      int cs = c0 ^ ((kk&7)<<2);
      float4 w0=*(const float4*)&Wt_[sub*64+kk*4  ][cs];
      float4 w1=*(const float4*)&Wt_[sub*64+kk*4+1][cs];
      float4 w2=*(const float4*)&Wt_[sub*64+kk*4+2][cs];
      float4 w3=*(const float4*)&Wt_[sub*64+kk*4+3][cs];
      acc0+=a4.x*w0.x; acc1+=a4.x*w0.y; acc2+=a4.x*w0.z; acc3+=a4.x*w0.w;
      acc0+=a4.y*w1.x; acc1+=a4.y*w1.y; acc2+=a4.y*w1.z; acc3+=a4.y*w1.w;
      acc0+=a4.z*w2.x; acc1+=a4.z*w2.y; acc2+=a4.z*w2.z; acc3+=a4.z*w2.w;
      acc0+=a4.w*w3.x; acc1+=a4.w*w3.y; acc2+=a4.w*w3.z; acc3+=a4.w*w3.w;
    }
    lds_barrier();   // reads done before next overwrite
  }
  Lc_[sub*16+tb][c0]=acc0; Lc_[sub*16+tb][c0+1]=acc1;
  Lc_[sub*16+tb][c0+2]=acc2; Lc_[sub*16+tb][c0+3]=acc3;
  __syncthreads();
  if (tid < 256) {
    int tb2 = tid>>4, jl = tid&15;
    int cc0 = jl*4;
    int col = col0 + cc0;
    float4 o;
    o.x = Lc_[tb2][cc0]  +Lc_[16+tb2][cc0]   + p.b_p[col];
    o.y = Lc_[tb2][cc0+1]+Lc_[16+tb2][cc0+1] + p.b_p[col+1];
    o.z = Lc_[tb2][cc0+2]+Lc_[16+tb2][cc0+2] + p.b_p[col+2];
    o.w = Lc_[tb2][cc0+3]+Lc_[16+tb2][cc0+3] + p.b_p[col+3];
    *(float4*)&p.y[(size_t)((b0+tb2)*LL + tprev)*OO + col] = o;
  }
  __syncthreads();
}

__global__ __launch_bounds__(NT, 2) void dnc_all(Params p) {
  __shared__ __align__(16) float smem[SMEM_F];
  __shared__ float red[8];
  const int blk = blockIdx.x, tid = threadIdx.x;
  const int NB = gridDim.x;
  unsigned bnum = 0;

  // ---------------- P0: init ----------------
  {
    for (int b = blk; b < BB; b += NB) {
      float4 z4 = make_float4(0.f,0.f,0.f,0.f);
      float4* m4 = (float4*)(p.mem + (size_t)b*MM*HSZ);
      for (int i = tid; i < (MM*HSZ)/4; i += NT) m4[i] = z4;
    }
    int gidx = blk*NT + tid;
    for (int i = gidx; i < BB*HH; i += NB*NT) dstore(&p.h[i], 0.f);
    for (int b = blk; b < BB; b += NB) {
      __syncthreads();
      for (int i = tid; i < CIN; i += NT)
        smem[i] = (i < EE) ? p.x_emb[(size_t)(b*LL)*EE + i] : 0.f;
      __syncthreads();
      float s = 0.f;
      for (int i = tid; i < CIN; i += NT) s += smem[i];
      float mu = bsum(s, red) * (1.f/CIN);
      float ss = 0.f;
      for (int i = tid; i < CIN; i += NT) { float d = smem[i]-mu; ss += d*d; }
      float rstd = rsqrtf(bsum(ss, red)*(1.f/CIN) + EPSF);
      for (int i = tid; i < CIN; i += NT)
        dstore(&p.ci[b*CIN+i], (smem[i]-mu)*rstd*p.ln_in_g[i] + p.ln_in_b[i]);
    }
  }
  gbar(p.bar, (++bnum)*NB);

  for (int t = 0; t < LL; ++t) {
    const float* hprev = p.h + (t & 1) * (BB*HH);
    float* hnew = p.h + ((t+1) & 1) * (BB*HH);

    // -------- P1: gates GEMM + LSTM; lds_barrier keeps W/A prefetch in flight --------
    for (int w = blk; w < 256; w += NB) {
      int cgp = w & 63, bg = w >> 6;
      int sub = tid >> 8, stid = tid & 255;
      int tb = stid >> 4, cq = stid & 15;
      int ar = tb, ac = cq << 2;
      int b0 = bg*16, j0 = cgp*16;
      float (*A_)[68]  = (float(*)[68])smem;
      float (*Wt_)[68] = (float(*)[68])(smem+2176);
      float (*Gv_)[68] = (float(*)[68])(smem+10880);
      int c0 = cq*4;
      float acc0=0,acc1=0,acc2=0,acc3=0;
      float2 a01, a23; float4 wPre[4];
      const int NIT = 14;  // 6 (ci, K=768) + 8 (h, K=1024) per sub
      // preload iter 0
      {
        const float* As = p.ci; const float* Ws = p.w_ih; int K = CIN;
        int k0 = sub*64;
        const float* ap = &As[(b0+ar)*K + k0 + ac];
        a01 = dload2(ap); a23 = dload2(ap+2);
        #pragma unroll
        for (int i2=0;i2<4;++i2){
          int idx2 = i2*256 + stid; int ccl = idx2>>4; int kq = (idx2&15)<<2;
          int gate = ccl>>4, jl = ccl&15;
          wPre[i2] = *(const float4*)&Ws[(size_t)(gate*HH + j0 + jl)*K + k0 + kq];
        }
      }
      for (int it=0; it<NIT; ++it){
        // write LDS from regs (compiler inserts counted vmcnt waits here)
        A_[sub*16+ar][ac]=a01.x; A_[sub*16+ar][ac+1]=a01.y;
        A_[sub*16+ar][ac+2]=a23.x; A_[sub*16+ar][ac+3]=a23.y;
        #pragma unroll
        for (int i2=0;i2<4;++i2){
          int idx2 = i2*256 + stid; int ccl = idx2>>4; int kq = (idx2&15)<<2;
          int swz = ((idx2&15)&7)<<2;
          int col = ccl ^ swz;
          Wt_[sub*64+kq  ][col]=wPre[i2].x; Wt_[sub*64+kq+1][col]=wPre[i2].y;
          Wt_[sub*64+kq+2][col]=wPre[i2].z; Wt_[sub*64+kq+3][col]=wPre[i2].w;
        }
        // issue prefetch for it+1 (in flight across both barriers + compute)
        int nx = (it+1 < NIT) ? it+1 : it;
        {
          const float* As; const float* Ws; int K, k0;
          if (nx < 6){ As = p.ci;  Ws = p.w_ih; K = CIN; k0 = (nx*2 + sub)*64; }
          else       { As = hprev; Ws = p.w_hh; K = HH;  k0 = ((nx-6)*2 + sub)*64; }
          const float* ap = &As[(b0+ar)*K + k0 + ac];
          a01 = dload2(ap); a23 = dload2(ap+2);
          #pragma unroll
          for (int i2=0;i2<4;++i2){
            int idx2 = i2*256 + stid; int ccl = idx2>>4; int kq = (idx2&15)<<2;
            int gate = ccl>>4, jl = ccl&15;
            wPre[i2] = *(const float4*)&Ws[(size_t)(gate*HH + j0 + jl)*K + k0 + kq];
          }
        }
        lds_barrier();   // LDS tile visible; vmcnt NOT drained
        #pragma unroll
        for (int kk=0;kk<16;++kk){
          float4 a4 = *(const float4*)&A_[sub*16+tb][kk*4];
          int cs = c0 ^ ((kk&7)<<2);
          float4 w0=*(const float4*)&Wt_[sub*64+kk*4  ][cs];
          float4 w1=*(const float4*)&Wt_[sub*64+kk*4+1][cs];
          float4 w2=*(const float4*)&Wt_[sub*64+kk*4+2][cs];
          float4 w3=*(const float4*)&Wt_[sub*64+kk*4+3][cs];
          acc0+=a4.x*w0.x; acc1+=a4.x*w0.y; acc2+=a4.x*w0.z; acc3+=a4.x*w0.w;
          acc0+=a4.y*w1.x; acc1+=a4.y*w1.y; acc2+=a4.y*w1.z; acc3+=a4.y*w1.w;
          acc0+=a4.z*w2.x; acc1+=a4.z*w2.y; acc2+=a4.z*w2.z; acc3+=a4.z*w2.w;
          acc0+=a4.w*w3.x; acc1+=a4.w*w3.y; acc2+=a4.w*w3.z; acc3+=a4.w*w3.w;
        }
        lds_barrier();   // reads done before next overwrite
      }
      Gv_[sub*16+tb][c0]=acc0; Gv_[sub*16+tb][c0+1]=acc1;
      Gv_[sub*16+tb][c0+2]=acc2; Gv_[sub*16+tb][c0+3]=acc3;
      __syncthreads();
      if (tid < 256) {
        int tb2 = tid>>4, jl = tid&15;
        int r0 = 0*HH + j0 + jl, r1 = 1*HH + j0 + jl, r2 = 2*HH + j0 + jl, r3 = 3*HH + j0 + jl;
        float gi = Gv_[tb2][jl]    + Gv_[16+tb2][jl]    + p.b_ih[r0]+p.b_hh[r0];
        float gf = Gv_[tb2][16+jl] + Gv_[16+tb2][16+jl] + p.b_ih[r1]+p.b_hh[r1];
        float gg = Gv_[tb2][32+jl] + Gv_[16+tb2][32+jl] + p.b_ih[r2]+p.b_hh[r2];
        float go = Gv_[tb2][48+jl] + Gv_[16+tb2][48+jl] + p.b_ih[r3]+p.b_hh[r3];
        int idx3 = (b0+tb2)*HH + j0 + jl;
        float cold = (t==0) ? 0.f : p.c[idx3];   // c tile-local (stable tile->block map)
        float cn = sigm(gf)*cold + sigm(gi)*tanhf(gg);
        float hv = sigm(go)*tanhf(cn);
        p.c[idx3] = cn;
        dstore(&hnew[idx3], hv);
        if (t == LL-1) { p.ht[idx3] = hv; p.ct[idx3] = cn; }
      }
      __syncthreads();
    }
    gbar(p.bar, (++bnum)*NB);

    // -------- Pb: heads+mem (blocks owning b) || logits(t-1) (next 64 blocks) --------
    for (int b = blk; b < BB; b += NB) {
      heads_b(p, b, tid, hnew, smem, red);
      __syncthreads();
      mem_b(p, b, tid, t, smem, red);
      __syncthreads();
    }
    if (t > 0) {
      for (int w = blk; w < 128; w += NB)
        if (w >= 64) logits_tile(p, w-64, tid, t-1, smem);
    }
    gbar(p.bar, (++bnum)*NB);
  }

  // ---------------- finale: logits(255) ----------------
  for (int w = blk; w < 128; w += NB)
    if (w >= 64) logits_tile(p, w-64, tid, LL-1, smem);
}

extern "C" void kernel_launch(void* const* d_in, const int* in_sizes, int n_in,
                              void* d_out, int out_size, void* d_ws, size_t ws_size,
                              hipStream_t stream) {
  Params prm;
  prm.x_emb  = (const float*)d_in[0];
  prm.ln_in_g= (const float*)d_in[1];
  prm.ln_in_b= (const float*)d_in[2];
  prm.w_ih   = (const float*)d_in[3];
  prm.w_hh   = (const float*)d_in[4];
  prm.b_ih   = (const float*)d_in[5];
  prm.b_hh   = (const float*)d_in[6];
  prm.ln_c_g = (const float*)d_in[7];
  prm.ln_c_b = (const float*)d_in[8];
  prm.w_rk   = (const float*)d_in[9];
  prm.b_rk   = (const float*)d_in[10];
  prm.w_wk   = (const float*)d_in[11];
  prm.b_wk   = (const float*)d_in[12];
  prm.w_ws   = (const float*)d_in[13];
  prm.b_ws   = (const float*)d_in[14];
  prm.w_er   = (const float*)d_in[15];
  prm.b_er   = (const float*)d_in[16];
  prm.w_ad   = (const float*)d_in[17];
  prm.b_ad   = (const float*)d_in[18];
  prm.ln_rk_g= (const float*)d_in[19];
  prm.ln_rk_b= (const float*)d_in[20];
  prm.ln_wk_g= (const float*)d_in[21];
  prm.ln_wk_b= (const float*)d_in[22];
  prm.ln_m_g = (const float*)d_in[23];
  prm.ln_m_b = (const float*)d_in[24];
  prm.ln_o_g = (const float*)d_in[25];
  prm.ln_o_b = (const float*)d_in[26];
  prm.w_p    = (const float*)d_in[27];
  prm.b_p    = (const float*)d_in[28];

  float* out = (float*)d_out;
  prm.y   = out + OUT_Y;
  prm.mem = out + OUT_MEM;
  prm.ht  = out + OUT_HT;
  prm.ct  = out + OUT_CT;

  prm.bar = (unsigned*)d_ws;
  hipMemsetAsync(d_ws, 0, 64, stream);

  float* ws = (float*)((char*)d_ws + 256);
  size_t o = 0;
  prm.h     = ws + o; o += 2*BB*HH;
  prm.c     = ws + o; o += BB*HH;
  prm.ci    = ws + o; o += BB*CIN;
  prm.orow  = ws + o; o += 2*BB*PO;

  int dev = 0;
  hipGetDevice(&dev);
  int ncu = 0;
  hipDeviceGetAttribute(&ncu, hipDeviceAttributeMultiprocessorCount, dev);
  if (ncu <= 0) ncu = 64;
  int nb = ncu < NBLK ? ncu : NBLK;
  int nbp = 1;
  while (nbp * 2 <= nb) nbp *= 2;

  dnc_all<<<dim3(nbp), dim3(NT), 0, stream>>>(prm);
}

// Round 9
// 33916.348 us; speedup vs baseline: 4.1392x; 1.5193x over previous
//
#include <hip/hip_runtime.h>
#include <math.h>

#define BB 64
#define LL 256
#define EE 512
#define HH 1024
#define MM 2048
#define HSZ 64
#define RR 4
#define CIN 768
#define PO 1280
#define OO 1024
#define EPSF 1e-5f
#define NBLK 256
#define NT 512

// ---- d_out layout (float offsets) ----
#define OUT_Y    0
#define OUT_MEM  (BB * LL * OO)
#define OUT_HT   (OUT_MEM + BB * MM * HSZ)
#define OUT_CT   (OUT_HT + BB * HH)

// ---- persistent LDS region (floats, offsets into smem) ----
#define P_HN   10368
#define P_RKN  (P_HN + 1024)
#define P_WKN  (P_RKN + 256)
#define P_ERS  (P_WKN + 64)
#define P_ADS  (P_ERS + 64)
#define P_WSS  (P_ADS + 64)
#define SMEM_F 13056

struct Params {
  const float *x_emb, *ln_in_g, *ln_in_b, *w_ih, *w_hh, *b_ih, *b_hh;
  const float *ln_c_g, *ln_c_b, *w_rk, *b_rk, *w_wk, *b_wk, *w_ws, *b_ws;
  const float *w_er, *b_er, *w_ad, *b_ad, *ln_rk_g, *ln_rk_b, *ln_wk_g, *ln_wk_b;
  const float *ln_m_g, *ln_m_b, *ln_o_g, *ln_o_b, *w_p, *b_p;
  float *y, *mem, *ht, *ct;
  float *h, *c, *ci, *orow;           // orow [2][BB][PO]
  unsigned short *wih16, *whh16, *wp16, *whd16;   // bf16 weight mirrors (d_ws)
  unsigned *bar;
};

__device__ __forceinline__ float sigm(float x){ return 1.f/(1.f+expf(-x)); }

// bf16 helpers: unpack low/high bf16 of a uint; RNE pack of 2 floats
__device__ __forceinline__ float bl(unsigned u){ return __uint_as_float(u<<16); }
__device__ __forceinline__ float bh(unsigned u){ return __uint_as_float(u & 0xffff0000u); }
__device__ __forceinline__ unsigned pk2(float a, float b){
  unsigned ua = __float_as_uint(a), ub = __float_as_uint(b);
  ua = (ua + 0x7fffu + ((ua>>16)&1u)) >> 16;
  ub = (ub + 0x7fffu + ((ub>>16)&1u)) >> 16;
  return ua | (ub<<16);
}

// agent-scope coherent accessors for CROSS-BLOCK tensors only
__device__ __forceinline__ float dload(const float* p){
  return __hip_atomic_load(p, __ATOMIC_RELAXED, __HIP_MEMORY_SCOPE_AGENT);
}
__device__ __forceinline__ float2 dload2(const float* p){
  unsigned long long u = __hip_atomic_load((const unsigned long long*)p,
                                           __ATOMIC_RELAXED, __HIP_MEMORY_SCOPE_AGENT);
  float2 r; r.x = __uint_as_float((unsigned)(u & 0xffffffffull));
  r.y = __uint_as_float((unsigned)(u >> 32)); return r;
}
__device__ __forceinline__ void dstore(float* p, float v){
  __hip_atomic_store(p, v, __ATOMIC_RELAXED, __HIP_MEMORY_SCOPE_AGENT);
}
__device__ __forceinline__ void dstoreu(unsigned* p, unsigned v){
  __hip_atomic_store(p, v, __ATOMIC_RELAXED, __HIP_MEMORY_SCOPE_AGENT);
}

// LDS-only barrier (keeps global prefetch in flight across barrier)
__device__ __forceinline__ void lds_barrier() {
  asm volatile("s_waitcnt lgkmcnt(0)" ::: "memory");
  __builtin_amdgcn_sched_barrier(0);
  __builtin_amdgcn_s_barrier();
  __builtin_amdgcn_sched_barrier(0);
}

// monotone count-up grid barrier (no L2 flush; cross-block data via agent ops)
__device__ __forceinline__ void gbar(unsigned* bar, unsigned target) {
  __syncthreads();
  if (threadIdx.x == 0) {
    asm volatile("s_waitcnt vmcnt(0)" ::: "memory");
    __hip_atomic_fetch_add(bar, 1u, __ATOMIC_RELAXED, __HIP_MEMORY_SCOPE_AGENT);
    while (__hip_atomic_load(bar, __ATOMIC_RELAXED, __HIP_MEMORY_SCOPE_AGENT) < target) {
      __builtin_amdgcn_s_sleep(8);
    }
    asm volatile("" ::: "memory");
  }
  __syncthreads();
}

__device__ __forceinline__ float bsum(float v, volatile float* red){
  __syncthreads();
  for (int o=32;o>0;o>>=1) v += __shfl_down(v,o,64);
  int w = threadIdx.x>>6;
  if ((threadIdx.x&63)==0) red[w]=v;
  __syncthreads();
  return red[0]+red[1]+red[2]+red[3]+red[4]+red[5]+red[6]+red[7];
}
__device__ __forceinline__ float bmax(float v, volatile float* red){
  __syncthreads();
  for (int o=32;o>0;o>>=1) v = fmaxf(v,__shfl_down(v,o,64));
  int w = threadIdx.x>>6;
  if ((threadIdx.x&63)==0) red[w]=v;
  __syncthreads();
  float a = fmaxf(fmaxf(red[0],red[1]),fmaxf(red[2],red[3]));
  float b = fmaxf(fmaxf(red[4],red[5]),fmaxf(red[6],red[7]));
  return fmaxf(a,b);
}

__device__ __forceinline__ float row_score(const float4* v, const float* wk,
                                           const float* g, const float* bt){
  float sum=0.f;
  #pragma unroll
  for (int i=0;i<16;++i) sum += v[i].x+v[i].y+v[i].z+v[i].w;
  float mu = sum*(1.f/64.f);
  float ssq=0.f;
  #pragma unroll
  for (int i=0;i<16;++i){ float dx=v[i].x-mu,dy=v[i].y-mu,dz=v[i].z-mu,dw=v[i].w-mu;
                          ssq+=dx*dx+dy*dy+dz*dz+dw*dw; }
  float rstd = rsqrtf(ssq*(1.f/64.f)+EPSF);
  float sc=0.f;
  #pragma unroll
  for (int i=0;i<16;++i){ int h=i*4;
    sc += ((v[i].x-mu)*rstd*g[h  ]+bt[h  ])*wk[h  ];
    sc += ((v[i].y-mu)*rstd*g[h+1]+bt[h+1])*wk[h+1];
    sc += ((v[i].z-mu)*rstd*g[h+2]+bt[h+2])*wk[h+2];
    sc += ((v[i].w-mu)*rstd*g[h+3]+bt[h+3])*wk[h+3];
  }
  return sc;
}

// load one bf16 mem row (64 elems) into float4 rr[16]
__device__ __forceinline__ void load_row16(const unsigned short* rp, float4* rr){
  const uint4* r16 = (const uint4*)rp;
  #pragma unroll
  for (int j=0;j<8;++j){
    uint4 q = r16[j];
    rr[2*j]   = make_float4(bl(q.x),bh(q.x),bl(q.y),bh(q.y));
    rr[2*j+1] = make_float4(bl(q.z),bh(q.z),bl(q.w),bh(q.w));
  }
}
__device__ __forceinline__ void store_row16(unsigned short* rp, const float4* rr){
  uint4* r16 = (uint4*)rp;
  #pragma unroll
  for (int j=0;j<8;++j){
    uint4 q;
    q.x = pk2(rr[2*j].x,   rr[2*j].y);
    q.y = pk2(rr[2*j].z,   rr[2*j].w);
    q.z = pk2(rr[2*j+1].x, rr[2*j+1].y);
    q.w = pk2(rr[2*j+1].z, rr[2*j+1].w);
    r16[j] = q;
  }
}

// heads for one b -> persistent LDS (bf16 weights, fp32 everything else)
__device__ void heads_b(const Params& p, int b, int tid, const float* hnew,
                        float* smem, volatile float* red){
  float* raw  = smem;            // 449
  float* pHn  = smem + P_HN;
  float2 hv = dload2(&hnew[b*HH + tid*2]);
  float s = bsum(hv.x + hv.y, red);
  float mu = s * (1.f/HH);
  float d0 = hv.x-mu, d1 = hv.y-mu;
  float ssq = bsum(d0*d0 + d1*d1, red);
  float rstd = rsqrtf(ssq*(1.f/HH)+EPSF);
  pHn[tid*2]   = d0*rstd*p.ln_c_g[tid*2]   + p.ln_c_b[tid*2];
  pHn[tid*2+1] = d1*rstd*p.ln_c_g[tid*2+1] + p.ln_c_b[tid*2+1];
  __syncthreads();
  if (tid < 449) {
    int gr = tid;
    float bias;
    if (gr < 256)      bias = p.b_rk[gr];
    else if (gr < 320) bias = p.b_wk[gr-256];
    else if (gr == 320)bias = p.b_ws[0];
    else if (gr < 385) bias = p.b_er[gr-321];
    else               bias = p.b_ad[gr-385];
    const unsigned short* wr16 = p.whd16 + (size_t)gr*HH;
    float acc = bias;
    #pragma unroll 4
    for (int k=0;k<HH;k+=8){
      uint4 q = *(const uint4*)&wr16[k];
      acc += bl(q.x)*pHn[k  ] + bh(q.x)*pHn[k+1] + bl(q.y)*pHn[k+2] + bh(q.y)*pHn[k+3]
           + bl(q.z)*pHn[k+4] + bh(q.z)*pHn[k+5] + bl(q.w)*pHn[k+6] + bh(q.w)*pHn[k+7];
    }
    raw[tid] = acc;
  }
  __syncthreads();
  if (tid < 256) {
    int l = tid & 63;
    float v = raw[tid];
    float sv=v; for(int o=32;o>0;o>>=1) sv += __shfl_xor(sv,o,64);
    float m2 = sv*(1.f/64.f);
    float d = v-m2; float sq=d*d;
    for(int o=32;o>0;o>>=1) sq += __shfl_xor(sq,o,64);
    float rs = rsqrtf(sq*(1.f/64.f)+EPSF);
    smem[P_RKN + tid] = d*rs*p.ln_rk_g[l] + p.ln_rk_b[l];
  } else if (tid < 320) {
    int l = tid - 256;
    float v = raw[256+l];
    float sv=v; for(int o=32;o>0;o>>=1) sv += __shfl_xor(sv,o,64);
    float m2 = sv*(1.f/64.f);
    float d=v-m2; float sq=d*d;
    for(int o=32;o>0;o>>=1) sq += __shfl_xor(sq,o,64);
    float rs = rsqrtf(sq*(1.f/64.f)+EPSF);
    smem[P_WKN + l] = d*rs*p.ln_wk_g[l] + p.ln_wk_b[l];
  } else if (tid < 384) {
    int l = tid - 320; smem[P_ERS + l] = sigm(raw[321+l]);
  } else if (tid < 448) {
    int l = tid - 384; smem[P_ADS + l] = tanhf(raw[385+l]);
  } else if (tid == 448) {
    smem[P_WSS] = sigm(raw[320]);
  }
}

// memory pipeline for one b; mem stored bf16 in first half of this block's memT slice
__device__ void mem_b(const Params& p, int b, int tid, int t, float* smem, volatile float* red){
  float* bcg = smem;            // 128
  float* sw  = smem + 128;      // 2048
  float* srd = smem + 2176;     // 8192
  float* pHn  = smem + P_HN;
  float* pRkn = smem + P_RKN;
  float* pWkn = smem + P_WKN;
  float* pErs = smem + P_ERS;
  float* pAds = smem + P_ADS;
  if (tid < 64) { bcg[tid] = p.ln_m_g[tid]; bcg[64+tid] = p.ln_m_b[tid]; }
  __syncthreads();
  float wstr = smem[P_WSS];
  unsigned short* mb16 = (unsigned short*)(p.mem + (size_t)b*MM*HSZ);

  // pass A: write scores
  for (int k=0;k<4;++k){
    int m = k*NT + tid;
    float4 rr[16];
    load_row16(mb16 + (size_t)m*HSZ, rr);
    sw[m] = row_score(rr, pWkn, bcg, bcg+64);
  }
  __syncthreads();
  float mx = -3.4e38f;
  #pragma unroll
  for (int k=0;k<4;++k) mx = fmaxf(mx, sw[k*NT+tid]);
  mx = bmax(mx, red);
  float se = 0.f;
  #pragma unroll
  for (int k=0;k<4;++k) se += expf(sw[k*NT+tid]-mx);
  se = bsum(se, red);
  float winv = wstr / se;
  #pragma unroll
  for (int k=0;k<4;++k){ int m=k*NT+tid; sw[m] = expf(sw[m]-mx)*winv; }

  // pass B: update rows + read scores
  for (int k=0;k<4;++k){
    int m = k*NT + tid;
    unsigned short* rp = mb16 + (size_t)m*HSZ;
    float4 rr[16];
    load_row16(rp, rr);
    float ww = sw[m];
    #pragma unroll
    for (int i=0;i<16;++i){ int h=i*4;
      rr[i].x = rr[i].x*(1.f-ww*pErs[h  ]) + ww*pAds[h  ];
      rr[i].y = rr[i].y*(1.f-ww*pErs[h+1]) + ww*pAds[h+1];
      rr[i].z = rr[i].z*(1.f-ww*pErs[h+2]) + ww*pAds[h+2];
      rr[i].w = rr[i].w*(1.f-ww*pErs[h+3]) + ww*pAds[h+3];
    }
    store_row16(rp, rr);
    float sum=0.f;
    #pragma unroll
    for (int i=0;i<16;++i) sum += rr[i].x+rr[i].y+rr[i].z+rr[i].w;
    float mu = sum*(1.f/64.f);
    float ssq=0.f;
    #pragma unroll
    for (int i=0;i<16;++i){ float dx=rr[i].x-mu,dy=rr[i].y-mu,dz=rr[i].z-mu,dw=rr[i].w-mu;
                            ssq+=dx*dx+dy*dy+dz*dz+dw*dw; }
    float rstd = rsqrtf(ssq*(1.f/64.f)+EPSF);
    float t0=0,t1=0,t2=0,t3=0;
    #pragma unroll
    for (int i=0;i<16;++i){ int h=i*4;
      float n0=(rr[i].x-mu)*rstd*bcg[h  ]+bcg[64+h  ];
      float n1=(rr[i].y-mu)*rstd*bcg[h+1]+bcg[64+h+1];
      float n2=(rr[i].z-mu)*rstd*bcg[h+2]+bcg[64+h+2];
      float n3=(rr[i].w-mu)*rstd*bcg[h+3]+bcg[64+h+3];
      t0 += n0*pRkn[h    ]+n1*pRkn[h+1    ]+n2*pRkn[h+2    ]+n3*pRkn[h+3    ];
      t1 += n0*pRkn[64+h ]+n1*pRkn[64+h+1 ]+n2*pRkn[64+h+2 ]+n3*pRkn[64+h+3 ];
      t2 += n0*pRkn[128+h]+n1*pRkn[128+h+1]+n2*pRkn[128+h+2]+n3*pRkn[128+h+3];
      t3 += n0*pRkn[192+h]+n1*pRkn[192+h+1]+n2*pRkn[192+h+2]+n3*pRkn[192+h+3];
    }
    srd[m] = t0; srd[2048+m] = t1; srd[4096+m] = t2; srd[6144+m] = t3;
  }
  __syncthreads();
  #pragma unroll
  for (int n=0;n<RR;++n){
    float mxn = -3.4e38f;
    #pragma unroll
    for (int k=0;k<4;++k) mxn = fmaxf(mxn, srd[n*2048+k*NT+tid]);
    mxn = bmax(mxn, red);
    float sen = 0.f;
    #pragma unroll
    for (int k=0;k<4;++k) sen += expf(srd[n*2048+k*NT+tid]-mxn);
    sen = bsum(sen, red);
    float rinv = 1.f/sen;
    #pragma unroll
    for (int k=0;k<4;++k){ int m=k*NT+tid; srd[n*2048+m] = expf(srd[n*2048+m]-mxn)*rinv; }
  }
  __syncthreads();
  // pass C: rv gather from bf16 rows; thread covers 2 adjacent hs cols, 16-way m split
  int hs2 = (tid & 31) * 2, wg = tid >> 5;
  float a00=0,a01=0,a10=0,a11=0,a20=0,a21=0,a30=0,a31=0;
  for (int m0=0; m0<MM; m0+=128){
    unsigned v[8];
    #pragma unroll
    for (int j=0;j<8;++j)
      v[j] = *(const unsigned*)&mb16[(size_t)(m0 + wg + 16*j)*HSZ + hs2];
    #pragma unroll
    for (int j=0;j<8;++j){
      int m = m0 + wg + 16*j;
      float vlo = bl(v[j]), vhi = bh(v[j]);
      float w0 = srd[m], w1 = srd[2048+m], w2 = srd[4096+m], w3 = srd[6144+m];
      a00 += w0*vlo; a01 += w0*vhi;
      a10 += w1*vlo; a11 += w1*vhi;
      a20 += w2*vlo; a21 += w2*vhi;
      a30 += w3*vlo; a31 += w3*vhi;
    }
  }
  __syncthreads();   // all srd (weights) reads done; reuse srd[0..4096) for partials
  srd[(0*16+wg)*64 + hs2] = a00; srd[(0*16+wg)*64 + hs2+1] = a01;
  srd[(1*16+wg)*64 + hs2] = a10; srd[(1*16+wg)*64 + hs2+1] = a11;
  srd[(2*16+wg)*64 + hs2] = a20; srd[(2*16+wg)*64 + hs2+1] = a21;
  srd[(3*16+wg)*64 + hs2] = a30; srd[(3*16+wg)*64 + hs2+1] = a31;
  __syncthreads();
  float rvv = 0.f;
  if (tid < 256) {
    int n2 = tid>>6, h2 = tid&63;
    #pragma unroll
    for (int g2=0; g2<16; ++g2) rvv += srd[(n2*16+g2)*64 + h2];
  }
  __syncthreads();   // partial reads done; srd reusable as row/cirow
  float* row   = srd;          // 1280
  float* cirow = srd + 1280;   // 768
  if (tid < 256) row[HH+tid] = rvv;
  for (int i=tid;i<HH;i+=NT) row[i] = pHn[i];
  __syncthreads();
  float s=0.f; for (int i=tid;i<PO;i+=NT) s+=row[i];
  float mu = bsum(s,red)*(1.f/PO);
  float ss=0.f; for (int i=tid;i<PO;i+=NT){ float d=row[i]-mu; ss+=d*d; }
  float rstd = rsqrtf(bsum(ss,red)*(1.f/PO)+EPSF);
  float* ob = p.orow + (size_t)(t&1)*BB*PO;
  for (int i=tid;i<PO;i+=NT)
    dstore(&ob[b*PO+i], (row[i]-mu)*rstd*p.ln_o_g[i]+p.ln_o_b[i]);
  if (t+1 < LL) {
    for (int i=tid;i<CIN;i+=NT)
      cirow[i] = (i<EE)? p.x_emb[(size_t)(b*LL+t+1)*EE+i] : row[HH+(i-EE)];
    __syncthreads();
    float s2=0.f; for (int i=tid;i<CIN;i+=NT) s2+=cirow[i];
    float mu2 = bsum(s2,red)*(1.f/CIN);
    float ss2=0.f; for (int i=tid;i<CIN;i+=NT){ float d=cirow[i]-mu2; ss2+=d*d; }
    float rstd2 = rsqrtf(bsum(ss2,red)*(1.f/CIN)+EPSF);
    for (int i=tid;i<CIN;i+=NT)
      dstore(&p.ci[b*CIN+i], (cirow[i]-mu2)*rstd2*p.ln_in_g[i]+p.ln_in_b[i]);
  }
}

// logits tile (bf16 w_p, K split across 2 subs, reg prefetch + swizzle)
__device__ void logits_tile(const Params& p, int w, int tid, int tprev, float* smem){
  const float* ob = p.orow + (size_t)(tprev&1)*BB*PO;
  int cgl = w & 15, bg = w >> 4;
  int sub = tid >> 8, stid = tid & 255;
  int tb = stid >> 4, cq = stid & 15;
  int ar = tb, ac = cq << 2;
  int b0 = bg*16, col0 = cgl*64;
  float (*A_)[68]  = (float(*)[68])smem;
  float (*Wt_)[68] = (float(*)[68])(smem+2176);
  float (*Lc_)[68] = (float(*)[68])(smem+10880);
  int c0 = cq*4;
  int cc = (sub*256 + stid) >> 3;            // fixed per thread? no: cc depends on (i2*256+stid)
  (void)cc;
  float acc0=0,acc1=0,acc2=0,acc3=0;
  float2 a01, a23; uint4 wPre[2];
  const int NIT = 10;
  {
    int k0 = (0*2 + sub)*64;
    const float* ap = &ob[(b0+ar)*PO + k0 + ac];
    a01 = dload2(ap); a23 = dload2(ap+2);
    #pragma unroll
    for (int i2=0;i2<2;++i2){
      int li = i2*256 + stid; int ccl = li>>3; int kq = (stid&7)*8;
      wPre[i2] = *(const uint4*)&p.wp16[(size_t)(col0+ccl)*PO + k0 + kq];
    }
  }
  for (int it=0; it<NIT; ++it){
    A_[sub*16+ar][ac]=a01.x; A_[sub*16+ar][ac+1]=a01.y;
    A_[sub*16+ar][ac+2]=a23.x; A_[sub*16+ar][ac+3]=a23.y;
    #pragma unroll
    for (int i2=0;i2<2;++i2){
      int li = i2*256 + stid; int ccl = li>>3; int kq = (stid&7)*8;
      float f0=bl(wPre[i2].x),f1=bh(wPre[i2].x),f2=bl(wPre[i2].y),f3=bh(wPre[i2].y);
      float f4=bl(wPre[i2].z),f5=bh(wPre[i2].z),f6=bl(wPre[i2].w),f7=bh(wPre[i2].w);
      Wt_[sub*64+kq  ][ccl ^ ((((kq  )>>2)&7)<<2)] = f0;
      Wt_[sub*64+kq+1][ccl ^ ((((kq+1)>>2)&7)<<2)] = f1;
      Wt_[sub*64+kq+2][ccl ^ ((((kq+2)>>2)&7)<<2)] = f2;
      Wt_[sub*64+kq+3][ccl ^ ((((kq+3)>>2)&7)<<2)] = f3;
      Wt_[sub*64+kq+4][ccl ^ ((((kq+4)>>2)&7)<<2)] = f4;
      Wt_[sub*64+kq+5][ccl ^ ((((kq+5)>>2)&7)<<2)] = f5;
      Wt_[sub*64+kq+6][ccl ^ ((((kq+6)>>2)&7)<<2)] = f6;
      Wt_[sub*64+kq+7][ccl ^ ((((kq+7)>>2)&7)<<2)] = f7;
    }
    int nx = (it+1 < NIT) ? it+1 : it;
    {
      int k0 = (nx*2 + sub)*64;
      const float* ap = &ob[(b0+ar)*PO + k0 + ac];
      a01 = dload2(ap); a23 = dload2(ap+2);
      #pragma unroll
      for (int i2=0;i2<2;++i2){
        int li = i2*256 + stid; int ccl = li>>3; int kq = (stid&7)*8;
        wPre[i2] = *(const uint4*)&p.wp16[(size_t)(col0+ccl)*PO + k0 + kq];
      }
    }
    lds_barrier();
    #pragma unroll
    for (int kk=0;kk<16;++kk){
      float4 a4 = *(const float4*)&A_[sub*16+tb][kk*4];
      int cs = c0 ^ ((kk&7)<<2);
      float4 w0=*(const float4*)&Wt_[sub*64+kk*4  ][cs];
      float4 w1=*(const float4*)&Wt_[sub*64+kk*4+1][cs];
      float4 w2=*(const float4*)&Wt_[sub*64+kk*4+2][cs];
      float4 w3=*(const float4*)&Wt_[sub*64+kk*4+3][cs];
      acc0+=a4.x*w0.x; acc1+=a4.x*w0.y; acc2+=a4.x*w0.z; acc3+=a4.x*w0.w;
      acc0+=a4.y*w1.x; acc1+=a4.y*w1.y; acc2+=a4.y*w1.z; acc3+=a4.y*w1.w;
      acc0+=a4.z*w2.x; acc1+=a4.z*w2.y; acc2+=a4.z*w2.z; acc3+=a4.z*w2.w;
      acc0+=a4.w*w3.x; acc1+=a4.w*w3.y; acc2+=a4.w*w3.z; acc3+=a4.w*w3.w;
    }
    lds_barrier();
  }
  Lc_[sub*16+tb][c0]=acc0; Lc_[sub*16+tb][c0+1]=acc1;
  Lc_[sub*16+tb][c0+2]=acc2; Lc_[sub*16+tb][c0+3]=acc3;
  __syncthreads();
  if (tid < 256) {
    int tb2 = tid>>4, jl = tid&15;
    int cc0 = jl*4;
    int col = col0 + cc0;
    float4 o;
    o.x = Lc_[tb2][cc0]  +Lc_[16+tb2][cc0]   + p.b_p[col];
    o.y = Lc_[tb2][cc0+1]+Lc_[16+tb2][cc0+1] + p.b_p[col+1];
    o.z = Lc_[tb2][cc0+2]+Lc_[16+tb2][cc0+2] + p.b_p[col+2];
    o.w = Lc_[tb2][cc0+3]+Lc_[16+tb2][cc0+3] + p.b_p[col+3];
    *(float4*)&p.y[(size_t)((b0+tb2)*LL + tprev)*OO + col] = o;
  }
  __syncthreads();
}

__global__ __launch_bounds__(NT, 2) void dnc_all(Params p) {
  __shared__ __align__(16) float smem[SMEM_F];
  __shared__ float red[8];
  const int blk = blockIdx.x, tid = threadIdx.x;
  const int NB = gridDim.x;
  unsigned bnum = 0;

  // ---------------- P0: init + one-time bf16 weight conversion ----------------
  {
    int gidx = blk*NT + tid, gstr = NB*NT;
    // bf16 weight mirrors (agent stores -> L3-visible to all blocks after gbar)
    for (int i = gidx; i < (4096*CIN)/2; i += gstr){
      float2 f = *(const float2*)&p.w_ih[2*(size_t)i];
      dstoreu((unsigned*)p.wih16 + i, pk2(f.x, f.y));
    }
    for (int i = gidx; i < (4096*HH)/2; i += gstr){
      float2 f = *(const float2*)&p.w_hh[2*(size_t)i];
      dstoreu((unsigned*)p.whh16 + i, pk2(f.x, f.y));
    }
    for (int i = gidx; i < (OO*PO)/2; i += gstr){
      float2 f = *(const float2*)&p.w_p[2*(size_t)i];
      dstoreu((unsigned*)p.wp16 + i, pk2(f.x, f.y));
    }
    for (int i = gidx; i < 449*512; i += gstr){
      int gr = i >> 9, kp = (i & 511)*2;
      const float* wrow = (gr<256)? p.w_rk + (size_t)gr*HH :
                          (gr<320)? p.w_wk + (size_t)(gr-256)*HH :
                          (gr==320)? p.w_ws :
                          (gr<385)? p.w_er + (size_t)(gr-321)*HH :
                                    p.w_ad + (size_t)(gr-385)*HH;
      dstoreu((unsigned*)p.whd16 + i, pk2(wrow[kp], wrow[kp+1]));
    }
    // mem16 zero (block-private slices, cached path)
    for (int b = blk; b < BB; b += NB) {
      unsigned* z = (unsigned*)(p.mem + (size_t)b*MM*HSZ);
      for (int i = tid; i < (MM*HSZ)/2; i += NT) z[i] = 0u;
    }
    for (int i = gidx; i < BB*HH; i += gstr) dstore(&p.h[i], 0.f);
    for (int b = blk; b < BB; b += NB) {
      __syncthreads();
      for (int i = tid; i < CIN; i += NT)
        smem[i] = (i < EE) ? p.x_emb[(size_t)(b*LL)*EE + i] : 0.f;
      __syncthreads();
      float s = 0.f;
      for (int i = tid; i < CIN; i += NT) s += smem[i];
      float mu = bsum(s, red) * (1.f/CIN);
      float ss = 0.f;
      for (int i = tid; i < CIN; i += NT) { float d = smem[i]-mu; ss += d*d; }
      float rstd = rsqrtf(bsum(ss, red)*(1.f/CIN) + EPSF);
      for (int i = tid; i < CIN; i += NT)
        dstore(&p.ci[b*CIN+i], (smem[i]-mu)*rstd*p.ln_in_g[i] + p.ln_in_b[i]);
    }
  }
  gbar(p.bar, (++bnum)*NB);

  for (int t = 0; t < LL; ++t) {
    const float* hprev = p.h + (t & 1) * (BB*HH);
    float* hnew = p.h + ((t+1) & 1) * (BB*HH);

    // -------- P1: gates GEMM + LSTM (bf16 weights) --------
    for (int w = blk; w < 256; w += NB) {
      int cgp = w & 63, bg = w >> 6;
      int sub = tid >> 8, stid = tid & 255;
      int tb = stid >> 4, cq = stid & 15;
      int ar = tb, ac = cq << 2;
      int b0 = bg*16, j0 = cgp*16;
      float (*A_)[68]  = (float(*)[68])smem;
      float (*Wt_)[68] = (float(*)[68])(smem+2176);
      float (*Gv_)[68] = (float(*)[68])(smem+10880);
      int c0 = cq*4;
      float acc0=0,acc1=0,acc2=0,acc3=0;
      float2 a01, a23; uint4 wPre[2];
      const int NIT = 14;
      {
        int k0 = sub*64;
        const float* ap = &p.ci[(b0+ar)*CIN + k0 + ac];
        a01 = dload2(ap); a23 = dload2(ap+2);
        #pragma unroll
        for (int i2=0;i2<2;++i2){
          int li = i2*256 + stid; int ccl = li>>3; int kq = (stid&7)*8;
          int gate = ccl>>4, jl = ccl&15;
          wPre[i2] = *(const uint4*)&p.wih16[(size_t)(gate*HH + j0 + jl)*CIN + k0 + kq];
        }
      }
      for (int it=0; it<NIT; ++it){
        A_[sub*16+ar][ac]=a01.x; A_[sub*16+ar][ac+1]=a01.y;
        A_[sub*16+ar][ac+2]=a23.x; A_[sub*16+ar][ac+3]=a23.y;
        #pragma unroll
        for (int i2=0;i2<2;++i2){
          int li = i2*256 + stid; int ccl = li>>3; int kq = (stid&7)*8;
          float f0=bl(wPre[i2].x),f1=bh(wPre[i2].x),f2=bl(wPre[i2].y),f3=bh(wPre[i2].y);
          float f4=bl(wPre[i2].z),f5=bh(wPre[i2].z),f6=bl(wPre[i2].w),f7=bh(wPre[i2].w);
          Wt_[sub*64+kq  ][ccl ^ ((((kq  )>>2)&7)<<2)] = f0;
          Wt_[sub*64+kq+1][ccl ^ ((((kq+1)>>2)&7)<<2)] = f1;
          Wt_[sub*64+kq+2][ccl ^ ((((kq+2)>>2)&7)<<2)] = f2;
          Wt_[sub*64+kq+3][ccl ^ ((((kq+3)>>2)&7)<<2)] = f3;
          Wt_[sub*64+kq+4][ccl ^ ((((kq+4)>>2)&7)<<2)] = f4;
          Wt_[sub*64+kq+5][ccl ^ ((((kq+5)>>2)&7)<<2)] = f5;
          Wt_[sub*64+kq+6][ccl ^ ((((kq+6)>>2)&7)<<2)] = f6;
          Wt_[sub*64+kq+7][ccl ^ ((((kq+7)>>2)&7)<<2)] = f7;
        }
        int nx = (it+1 < NIT) ? it+1 : it;
        {
          const float* As; const unsigned short* Ws16; int K, k0;
          if (nx < 6){ As = p.ci;  Ws16 = p.wih16; K = CIN; k0 = (nx*2 + sub)*64; }
          else       { As = hprev; Ws16 = p.whh16; K = HH;  k0 = ((nx-6)*2 + sub)*64; }
          const float* ap = &As[(b0+ar)*K + k0 + ac];
          a01 = dload2(ap); a23 = dload2(ap+2);
          #pragma unroll
          for (int i2=0;i2<2;++i2){
            int li = i2*256 + stid; int ccl = li>>3; int kq = (stid&7)*8;
            int gate = ccl>>4, jl = ccl&15;
            wPre[i2] = *(const uint4*)&Ws16[(size_t)(gate*HH + j0 + jl)*K + k0 + kq];
          }
        }
        lds_barrier();
        #pragma unroll
        for (int kk=0;kk<16;++kk){
          float4 a4 = *(const float4*)&A_[sub*16+tb][kk*4];
          int cs = c0 ^ ((kk&7)<<2);
          float4 w0=*(const float4*)&Wt_[sub*64+kk*4  ][cs];
          float4 w1=*(const float4*)&Wt_[sub*64+kk*4+1][cs];
          float4 w2=*(const float4*)&Wt_[sub*64+kk*4+2][cs];
          float4 w3=*(const float4*)&Wt_[sub*64+kk*4+3][cs];
          acc0+=a4.x*w0.x; acc1+=a4.x*w0.y; acc2+=a4.x*w0.z; acc3+=a4.x*w0.w;
          acc0+=a4.y*w1.x; acc1+=a4.y*w1.y; acc2+=a4.y*w1.z; acc3+=a4.y*w1.w;
          acc0+=a4.z*w2.x; acc1+=a4.z*w2.y; acc2+=a4.z*w2.z; acc3+=a4.z*w2.w;
          acc0+=a4.w*w3.x; acc1+=a4.w*w3.y; acc2+=a4.w*w3.z; acc3+=a4.w*w3.w;
        }
        lds_barrier();
      }
      Gv_[sub*16+tb][c0]=acc0; Gv_[sub*16+tb][c0+1]=acc1;
      Gv_[sub*16+tb][c0+2]=acc2; Gv_[sub*16+tb][c0+3]=acc3;
      __syncthreads();
      if (tid < 256) {
        int tb2 = tid>>4, jl = tid&15;
        int r0 = 0*HH + j0 + jl, r1 = 1*HH + j0 + jl, r2 = 2*HH + j0 + jl, r3 = 3*HH + j0 + jl;
        float gi = Gv_[tb2][jl]    + Gv_[16+tb2][jl]    + p.b_ih[r0]+p.b_hh[r0];
        float gf = Gv_[tb2][16+jl] + Gv_[16+tb2][16+jl] + p.b_ih[r1]+p.b_hh[r1];
        float gg = Gv_[tb2][32+jl] + Gv_[16+tb2][32+jl] + p.b_ih[r2]+p.b_hh[r2];
        float go = Gv_[tb2][48+jl] + Gv_[16+tb2][48+jl] + p.b_ih[r3]+p.b_hh[r3];
        int idx3 = (b0+tb2)*HH + j0 + jl;
        float cold = (t==0) ? 0.f : p.c[idx3];
        float cn = sigm(gf)*cold + sigm(gi)*tanhf(gg);
        float hv = sigm(go)*tanhf(cn);
        p.c[idx3] = cn;
        dstore(&hnew[idx3], hv);
        if (t == LL-1) { p.ht[idx3] = hv; p.ct[idx3] = cn; }
      }
      __syncthreads();
    }
    gbar(p.bar, (++bnum)*NB);

    // -------- Pb: heads+mem (blocks 0-63) || logits(t-1) (blocks 64-127) --------
    for (int b = blk; b < BB; b += NB) {
      heads_b(p, b, tid, hnew, smem, red);
      __syncthreads();
      mem_b(p, b, tid, t, smem, red);
      __syncthreads();
    }
    if (t > 0) {
      for (int w = blk; w < 128; w += NB)
        if (w >= 64) logits_tile(p, w-64, tid, t-1, smem);
    }
    gbar(p.bar, (++bnum)*NB);
  }

  // ---------------- finale: expand bf16 mem -> fp32 memT (in place, backward) ----------------
  for (int b = blk; b < BB; b += NB) {
    unsigned short* s16 = (unsigned short*)(p.mem + (size_t)b*MM*HSZ);
    float* dst = p.mem + (size_t)b*MM*HSZ;
    for (int hi = MM, lo = MM/2; hi > 1; hi = lo, lo >>= 1) {
      int nel = (hi-lo)*HSZ;
      for (int e = tid*8; e < nel; e += NT*8) {
        uint4 q = *(const uint4*)&s16[(size_t)lo*HSZ + e];
        float4* d = (float4*)&dst[(size_t)lo*HSZ + e];
        d[0] = make_float4(bl(q.x),bh(q.x),bl(q.y),bh(q.y));
        d[1] = make_float4(bl(q.z),bh(q.z),bl(q.w),bh(q.w));
      }
      __syncthreads();
    }
    if (tid == 0) {        // row 0: read all before writing (write covers bf16 rows 0-1)
      uint4 q[8];
      #pragma unroll
      for (int j=0;j<8;++j) q[j] = ((const uint4*)s16)[j];
      #pragma unroll
      for (int j=0;j<8;++j){
        ((float4*)dst)[2*j]   = make_float4(bl(q[j].x),bh(q[j].x),bl(q[j].y),bh(q[j].y));
        ((float4*)dst)[2*j+1] = make_float4(bl(q[j].z),bh(q[j].z),bl(q[j].w),bh(q[j].w));
      }
    }
    __syncthreads();
  }
  for (int w = blk; w < 128; w += NB)
    if (w >= 64) logits_tile(p, w-64, tid, LL-1, smem);
}

extern "C" void kernel_launch(void* const* d_in, const int* in_sizes, int n_in,
                              void* d_out, int out_size, void* d_ws, size_t ws_size,
                              hipStream_t stream) {
  Params prm;
  prm.x_emb  = (const float*)d_in[0];
  prm.ln_in_g= (const float*)d_in[1];
  prm.ln_in_b= (const float*)d_in[2];
  prm.w_ih   = (const float*)d_in[3];
  prm.w_hh   = (const float*)d_in[4];
  prm.b_ih   = (const float*)d_in[5];
  prm.b_hh   = (const float*)d_in[6];
  prm.ln_c_g = (const float*)d_in[7];
  prm.ln_c_b = (const float*)d_in[8];
  prm.w_rk   = (const float*)d_in[9];
  prm.b_rk   = (const float*)d_in[10];
  prm.w_wk   = (const float*)d_in[11];
  prm.b_wk   = (const float*)d_in[12];
  prm.w_ws   = (const float*)d_in[13];
  prm.b_ws   = (const float*)d_in[14];
  prm.w_er   = (const float*)d_in[15];
  prm.b_er   = (const float*)d_in[16];
  prm.w_ad   = (const float*)d_in[17];
  prm.b_ad   = (const float*)d_in[18];
  prm.ln_rk_g= (const float*)d_in[19];
  prm.ln_rk_b= (const float*)d_in[20];
  prm.ln_wk_g= (const float*)d_in[21];
  prm.ln_wk_b= (const float*)d_in[22];
  prm.ln_m_g = (const float*)d_in[23];
  prm.ln_m_b = (const float*)d_in[24];
  prm.ln_o_g = (const float*)d_in[25];
  prm.ln_o_b = (const float*)d_in[26];
  prm.w_p    = (const float*)d_in[27];
  prm.b_p    = (const float*)d_in[28];

  float* out = (float*)d_out;
  prm.y   = out + OUT_Y;
  prm.mem = out + OUT_MEM;
  prm.ht  = out + OUT_HT;
  prm.ct  = out + OUT_CT;

  prm.bar = (unsigned*)d_ws;
  hipMemsetAsync(d_ws, 0, 64, stream);

  float* ws = (float*)((char*)d_ws + 256);
  size_t o = 0;
  prm.h     = ws + o; o += 2*BB*HH;
  prm.c     = ws + o; o += BB*HH;
  prm.ci    = ws + o; o += BB*CIN;
  prm.orow  = ws + o; o += 2*BB*PO;
  prm.wih16 = (unsigned short*)(ws + o); o += (4096*CIN)/2;
  prm.whh16 = (unsigned short*)(ws + o); o += (4096*HH)/2;
  prm.wp16  = (unsigned short*)(ws + o); o += (OO*PO)/2;
  prm.whd16 = (unsigned short*)(ws + o); o += (449*HH)/2 + 64;

  int dev = 0;
  hipGetDevice(&dev);
  int ncu = 0;
  hipDeviceGetAttribute(&ncu, hipDeviceAttributeMultiprocessorCount, dev);
  if (ncu <= 0) ncu = 64;
  int nb = ncu < NBLK ? ncu : NBLK;
  int nbp = 1;
  while (nbp * 2 <= nb) nbp *= 2;

  dnc_all<<<dim3(nbp), dim3(NT), 0, stream>>>(prm);
}